// Round 2
// baseline (3080.465 us; speedup 1.0000x reference)
//
#include <hip/hip_runtime.h>
#include <math.h>

#define D_MODEL   1024
#define D_INNER   2048
#define HEADDIM   64
#define NHEADS    32
#define D_STATE   128
#define D_CONV    4
#define CONV_DIM  2304      // D_INNER + 2*D_STATE
#define D_IN_PROJ 4384      // 2*D_INNER + 2*D_STATE + NHEADS
#define LSEQ      2048
#define BATCH     2
#define NROWS     4096      // BATCH * LSEQ
#define NC        32        // chunks per batch (LSEQ / 64)

// ---------------------------------------------------------------------------
// GEMM:  C[m][n] = sum_k A[m*K + k] * B[n*K + k]    (both K-major, "NT")
// ---------------------------------------------------------------------------
#define BM 128
#define BN 128
#define BK 16
#define LDP 132

__global__ __launch_bounds__(256) void gemm_nt(
    const float* __restrict__ A, const float* __restrict__ B,
    float* __restrict__ C, int M, int N, int K) {
  __shared__ __align__(16) float sA[BK][LDP];
  __shared__ __align__(16) float sB[BK][LDP];
  const int tid = threadIdx.x;
  const int row0 = blockIdx.y * BM;
  const int col0 = blockIdx.x * BN;
  const int tx = tid & 15;
  const int ty = tid >> 4;

  float acc[8][8] = {};

  for (int k0 = 0; k0 < K; k0 += BK) {
    #pragma unroll
    for (int i = 0; i < 2; ++i) {
      int f  = tid + i * 256;
      int m  = f >> 2;
      int kq = f & 3;
      {
        int gm = row0 + m;
        float4 v = make_float4(0.f, 0.f, 0.f, 0.f);
        if (gm < M)
          v = *reinterpret_cast<const float4*>(&A[(size_t)gm * K + k0 + kq * 4]);
        sA[kq * 4 + 0][m] = v.x; sA[kq * 4 + 1][m] = v.y;
        sA[kq * 4 + 2][m] = v.z; sA[kq * 4 + 3][m] = v.w;
      }
      {
        int gn = col0 + m;
        float4 v = make_float4(0.f, 0.f, 0.f, 0.f);
        if (gn < N)
          v = *reinterpret_cast<const float4*>(&B[(size_t)gn * K + k0 + kq * 4]);
        sB[kq * 4 + 0][m] = v.x; sB[kq * 4 + 1][m] = v.y;
        sB[kq * 4 + 2][m] = v.z; sB[kq * 4 + 3][m] = v.w;
      }
    }
    __syncthreads();

    #pragma unroll
    for (int kk = 0; kk < BK; ++kk) {
      float4 a0 = *reinterpret_cast<const float4*>(&sA[kk][ty * 8]);
      float4 a1 = *reinterpret_cast<const float4*>(&sA[kk][ty * 8 + 4]);
      float4 b0 = *reinterpret_cast<const float4*>(&sB[kk][tx * 4]);
      float4 b1 = *reinterpret_cast<const float4*>(&sB[kk][64 + tx * 4]);
      float a[8] = {a0.x, a0.y, a0.z, a0.w, a1.x, a1.y, a1.z, a1.w};
      float b[8] = {b0.x, b0.y, b0.z, b0.w, b1.x, b1.y, b1.z, b1.w};
      #pragma unroll
      for (int i = 0; i < 8; ++i)
        #pragma unroll
        for (int j = 0; j < 8; ++j)
          acc[i][j] = fmaf(a[i], b[j], acc[i][j]);
    }
    __syncthreads();
  }

  #pragma unroll
  for (int i = 0; i < 8; ++i) {
    int gm = row0 + ty * 8 + i;
    if (gm >= M) continue;
    #pragma unroll
    for (int j = 0; j < 8; ++j) {
      int cn = (j < 4) ? (tx * 4 + j) : (64 + tx * 4 + (j - 4));
      int gn = col0 + cn;
      if (gn < N) C[(size_t)gm * N + gn] = acc[i][j];
    }
  }
}

// ---------------------------------------------------------------------------
// depthwise causal conv (K=4) + bias + silu
// ---------------------------------------------------------------------------
__global__ __launch_bounds__(256) void conv_silu_kernel(
    const float* __restrict__ zxbcdt, const float* __restrict__ conv_w,
    const float* __restrict__ conv_b, float* __restrict__ xconv) {
  const int c = blockIdx.x * 256 + threadIdx.x;
  const int l = blockIdx.y;
  const int b = blockIdx.z;
  const float* src = zxbcdt + ((size_t)b * LSEQ) * D_IN_PROJ + D_INNER + c;
  float w0 = conv_w[c * 4 + 0], w1 = conv_w[c * 4 + 1];
  float w2 = conv_w[c * 4 + 2], w3 = conv_w[c * 4 + 3];
  float acc = conv_b[c];
  if (l >= 3) acc = fmaf(w0, src[(size_t)(l - 3) * D_IN_PROJ], acc);
  if (l >= 2) acc = fmaf(w1, src[(size_t)(l - 2) * D_IN_PROJ], acc);
  if (l >= 1) acc = fmaf(w2, src[(size_t)(l - 1) * D_IN_PROJ], acc);
  acc = fmaf(w3, src[(size_t)l * D_IN_PROJ], acc);
  float s = acc / (1.f + expf(-acc));
  xconv[((size_t)b * LSEQ + l) * CONV_DIM + c] = s;
}

// ---------------------------------------------------------------------------
// dt = softplus(dt_raw + dt_bias)
// ---------------------------------------------------------------------------
__global__ __launch_bounds__(256) void dt_kernel(
    const float* __restrict__ zxbcdt, const float* __restrict__ dt_bias,
    float* __restrict__ dt_out) {
  int idx = blockIdx.x * 256 + threadIdx.x;
  int h = idx & 31;
  int row = idx >> 5;
  float x = zxbcdt[(size_t)row * D_IN_PROJ + (D_INNER + CONV_DIM) + h] + dt_bias[h];
  float dt = (x > 20.f) ? x : log1pf(expf(x));
  dt_out[idx] = dt;
}

// ---------------------------------------------------------------------------
// per-chunk inclusive cumsum of a_t = dt_t * A_h.  one wave per (b,c,h).
// ---------------------------------------------------------------------------
__global__ __launch_bounds__(256) void cumsum_kernel(
    const float* __restrict__ dt_s, const float* __restrict__ A_log,
    float* __restrict__ cumL) {
  int u = blockIdx.x * 4 + (threadIdx.x >> 6);   // ((b*NC + c)*NHEADS + h)
  int lane = threadIdx.x & 63;
  int h = u & 31;
  int bc = u >> 5;                                // b*NC + c
  int row = bc * 64 + lane;                       // = b*2048 + c*64 + lane
  float A = -expf(A_log[h]);
  float a = dt_s[(size_t)row * NHEADS + h] * A;
  #pragma unroll
  for (int off = 1; off < 64; off <<= 1) {
    float v = __shfl_up(a, off);
    if (lane >= off) a += v;
  }
  cumL[(size_t)u * 64 + lane] = a;
}

// ---------------------------------------------------------------------------
// inter-chunk: sequential over 32 chunks; H[p][n] in registers.
// grid: (b, h, pslab) = 2*32*4 = 256 WGs, 256 threads.
// thread: pg = tid>>4 (p within slab), ng = tid&15 (8-wide n block).
// writes Y_inter to y (init).
// ---------------------------------------------------------------------------
__global__ __launch_bounds__(256) void inter_kernel(
    const float* __restrict__ xconv, const float* __restrict__ dt_s,
    const float* __restrict__ cumL, float* __restrict__ y) {
  const int bi = blockIdx.x;          // ((b*NHEADS + h)*4 + ps)
  const int ps = bi & 3;
  const int h  = (bi >> 2) & 31;
  const int b  = bi >> 7;
  const int tid = threadIdx.x;
  const int pg = tid >> 4;
  const int ng = tid & 15;
  const int n0 = ng * 8;

  __shared__ __align__(16) float sC[64][132];
  __shared__ __align__(16) float sB[64][132];
  __shared__ float sx[64][17];
  __shared__ float sL[64], seL[64], sw[64];
  __shared__ float sYi[64][17];

  float H[8] = {};

  for (int c = 0; c < NC; ++c) {
    const int row0 = b * LSEQ + c * 64;
    const int u = (b * NC + c) * NHEADS + h;
    __syncthreads();
    // stage B, C (64 x 128 each)
    #pragma unroll
    for (int i = 0; i < 8; ++i) {
      int idx = tid + i * 256;        // 0..2047 float4 slots
      int r = idx >> 5, c4 = idx & 31;
      const float* src = &xconv[(size_t)(row0 + r) * CONV_DIM + D_INNER];
      float4 vb = *reinterpret_cast<const float4*>(&src[c4 * 4]);
      float4 vc = *reinterpret_cast<const float4*>(&src[D_STATE + c4 * 4]);
      *reinterpret_cast<float4*>(&sB[r][c4 * 4]) = vb;
      *reinterpret_cast<float4*>(&sC[r][c4 * 4]) = vc;
    }
    // stage x slab (64 x 16)
    #pragma unroll
    for (int i = 0; i < 4; ++i) {
      int idx = tid + i * 256;
      int r = idx >> 4, pp = idx & 15;
      sx[r][pp] = xconv[(size_t)(row0 + r) * CONV_DIM + h * 64 + ps * 16 + pp];
    }
    if (tid < 64) sL[tid] = cumL[(size_t)u * 64 + tid];
    __syncthreads();
    if (tid < 64) {
      float L = sL[tid];
      seL[tid] = expf(L);
      sw[tid]  = dt_s[(size_t)(row0 + tid) * NHEADS + h] * expf(sL[63] - L);
    }
    __syncthreads();

    // Y_inter[t][p] = exp(L_t) * sum_n C[t][n] * H[p][n]
    for (int t = 0; t < 64; ++t) {
      float4 c0 = *reinterpret_cast<const float4*>(&sC[t][n0]);
      float4 c1 = *reinterpret_cast<const float4*>(&sC[t][n0 + 4]);
      float part = c0.x * H[0] + c0.y * H[1] + c0.z * H[2] + c0.w * H[3]
                 + c1.x * H[4] + c1.y * H[5] + c1.z * H[6] + c1.w * H[7];
      part += __shfl_xor(part, 1);
      part += __shfl_xor(part, 2);
      part += __shfl_xor(part, 4);
      part += __shfl_xor(part, 8);
      if (ng == 0) sYi[t][pg] = seL[t] * part;
    }

    // H = exp(L63)*H + sum_s w_s * x[s][p] * B[s][n]
    float Dt = seL[63];
    #pragma unroll
    for (int j = 0; j < 8; ++j) H[j] *= Dt;
    for (int s = 0; s < 64; ++s) {
      float xw = sw[s] * sx[s][pg];
      float4 b0 = *reinterpret_cast<const float4*>(&sB[s][n0]);
      float4 b1 = *reinterpret_cast<const float4*>(&sB[s][n0 + 4]);
      H[0] = fmaf(xw, b0.x, H[0]); H[1] = fmaf(xw, b0.y, H[1]);
      H[2] = fmaf(xw, b0.z, H[2]); H[3] = fmaf(xw, b0.w, H[3]);
      H[4] = fmaf(xw, b1.x, H[4]); H[5] = fmaf(xw, b1.y, H[5]);
      H[6] = fmaf(xw, b1.z, H[6]); H[7] = fmaf(xw, b1.w, H[7]);
    }
    __syncthreads();
    // write Y_inter slab
    #pragma unroll
    for (int i = 0; i < 4; ++i) {
      int idx = tid + i * 256;
      int t = idx >> 4, pp = idx & 15;
      y[(size_t)(row0 + t) * D_INNER + h * 64 + ps * 16 + pp] = sYi[t][pp];
    }
  }
}

// ---------------------------------------------------------------------------
// intra-chunk: per (b,c,h): G = C@B^T (K=128), mask+decay, Y += M@X.
// grid 2048, 256 threads, 4x4 micro-tiles.
// ---------------------------------------------------------------------------
__global__ __launch_bounds__(256) void intra_kernel(
    const float* __restrict__ xconv, const float* __restrict__ dt_s,
    const float* __restrict__ cumL, float* __restrict__ y) {
  const int bi = blockIdx.x;        // (b*NC + c)*NHEADS + h
  const int h  = bi & 31;
  const int bc = bi >> 5;
  const int row0 = bc * 64;
  const int tid = threadIdx.x;
  const int tr = tid >> 4;
  const int tc = tid & 15;

  __shared__ __align__(16) float sX[64][68];
  __shared__ __align__(16) float sM[64][68];
  __shared__ float sCs[64][33];
  __shared__ float sBs[64][33];
  __shared__ float sdt[64], sL[64];

  // stage x (64x64), dt, L
  #pragma unroll
  for (int i = 0; i < 4; ++i) {
    int idx = tid + i * 256;
    int r = idx >> 4, c4 = idx & 15;
    float4 v = *reinterpret_cast<const float4*>(
        &xconv[(size_t)(row0 + r) * CONV_DIM + h * 64 + c4 * 4]);
    *reinterpret_cast<float4*>(&sX[r][c4 * 4]) = v;
  }
  if (tid < 64) {
    sdt[tid] = dt_s[(size_t)(row0 + tid) * NHEADS + h];
    sL[tid]  = cumL[(size_t)bi * 64 + tid];
  }

  // G[t][s] = sum_n C[t][n]*B[s][n], slabbed over n
  float acc[4][4] = {};
  for (int ns = 0; ns < 4; ++ns) {
    __syncthreads();
    #pragma unroll
    for (int i = 0; i < 2; ++i) {
      int idx = tid + i * 256;      // 0..511
      int r = idx >> 3, c4 = idx & 7;
      const float* src = &xconv[(size_t)(row0 + r) * CONV_DIM + D_INNER + ns * 32 + c4 * 4];
      float4 vb = *reinterpret_cast<const float4*>(src);
      float4 vc = *reinterpret_cast<const float4*>(src + D_STATE);
      sBs[r][c4 * 4 + 0] = vb.x; sBs[r][c4 * 4 + 1] = vb.y;
      sBs[r][c4 * 4 + 2] = vb.z; sBs[r][c4 * 4 + 3] = vb.w;
      sCs[r][c4 * 4 + 0] = vc.x; sCs[r][c4 * 4 + 1] = vc.y;
      sCs[r][c4 * 4 + 2] = vc.z; sCs[r][c4 * 4 + 3] = vc.w;
    }
    __syncthreads();
    for (int k = 0; k < 32; ++k) {
      float a0 = sCs[tr * 4 + 0][k], a1 = sCs[tr * 4 + 1][k];
      float a2 = sCs[tr * 4 + 2][k], a3 = sCs[tr * 4 + 3][k];
      float b0 = sBs[tc * 4 + 0][k], b1 = sBs[tc * 4 + 1][k];
      float b2 = sBs[tc * 4 + 2][k], b3 = sBs[tc * 4 + 3][k];
      acc[0][0] = fmaf(a0, b0, acc[0][0]); acc[0][1] = fmaf(a0, b1, acc[0][1]);
      acc[0][2] = fmaf(a0, b2, acc[0][2]); acc[0][3] = fmaf(a0, b3, acc[0][3]);
      acc[1][0] = fmaf(a1, b0, acc[1][0]); acc[1][1] = fmaf(a1, b1, acc[1][1]);
      acc[1][2] = fmaf(a1, b2, acc[1][2]); acc[1][3] = fmaf(a1, b3, acc[1][3]);
      acc[2][0] = fmaf(a2, b0, acc[2][0]); acc[2][1] = fmaf(a2, b1, acc[2][1]);
      acc[2][2] = fmaf(a2, b2, acc[2][2]); acc[2][3] = fmaf(a2, b3, acc[2][3]);
      acc[3][0] = fmaf(a3, b0, acc[3][0]); acc[3][1] = fmaf(a3, b1, acc[3][1]);
      acc[3][2] = fmaf(a3, b2, acc[3][2]); acc[3][3] = fmaf(a3, b3, acc[3][3]);
    }
  }

  // masked, decayed M into LDS
  #pragma unroll
  for (int i = 0; i < 4; ++i) {
    int t = tr * 4 + i;
    #pragma unroll
    for (int j = 0; j < 4; ++j) {
      int s = tc * 4 + j;
      float m = 0.f;
      if (s <= t) m = expf(sL[t] - sL[s]) * sdt[s] * acc[i][j];
      sM[t][s] = m;
    }
  }
  __syncthreads();

  // Y_intra = M @ X, add into y
  float o[4][4] = {};
  for (int s = 0; s < 64; ++s) {
    float a0 = sM[tr * 4 + 0][s], a1 = sM[tr * 4 + 1][s];
    float a2 = sM[tr * 4 + 2][s], a3 = sM[tr * 4 + 3][s];
    float4 xv = *reinterpret_cast<const float4*>(&sX[s][tc * 4]);
    o[0][0] = fmaf(a0, xv.x, o[0][0]); o[0][1] = fmaf(a0, xv.y, o[0][1]);
    o[0][2] = fmaf(a0, xv.z, o[0][2]); o[0][3] = fmaf(a0, xv.w, o[0][3]);
    o[1][0] = fmaf(a1, xv.x, o[1][0]); o[1][1] = fmaf(a1, xv.y, o[1][1]);
    o[1][2] = fmaf(a1, xv.z, o[1][2]); o[1][3] = fmaf(a1, xv.w, o[1][3]);
    o[2][0] = fmaf(a2, xv.x, o[2][0]); o[2][1] = fmaf(a2, xv.y, o[2][1]);
    o[2][2] = fmaf(a2, xv.z, o[2][2]); o[2][3] = fmaf(a2, xv.w, o[2][3]);
    o[3][0] = fmaf(a3, xv.x, o[3][0]); o[3][1] = fmaf(a3, xv.y, o[3][1]);
    o[3][2] = fmaf(a3, xv.z, o[3][2]); o[3][3] = fmaf(a3, xv.w, o[3][3]);
  }
  #pragma unroll
  for (int i = 0; i < 4; ++i) {
    int t = tr * 4 + i;
    float* dst = &y[(size_t)(row0 + t) * D_INNER + h * 64 + tc * 4];
    float4 cur = *reinterpret_cast<const float4*>(dst);
    cur.x += o[i][0]; cur.y += o[i][1]; cur.z += o[i][2]; cur.w += o[i][3];
    *reinterpret_cast<float4*>(dst) = cur;
  }
}

// ---------------------------------------------------------------------------
// y = (y + D_skip*xh) * silu(z);  RMSNorm
// ---------------------------------------------------------------------------
__global__ __launch_bounds__(256) void gate_rms_kernel(
    float* __restrict__ y, const float* __restrict__ zxbcdt,
    const float* __restrict__ xconv, const float* __restrict__ D_skip,
    const float* __restrict__ norm_w) {
  const int row = blockIdx.x;
  const int tid = threadIdx.x;
  float v[8];
  float acc = 0.f;
  #pragma unroll
  for (int i = 0; i < 8; ++i) {
    int d = i * 256 + tid;
    float ys = y[(size_t)row * D_INNER + d];
    float xh = xconv[(size_t)row * CONV_DIM + d];
    float Dh = D_skip[d >> 6];
    float z  = zxbcdt[(size_t)row * D_IN_PROJ + d];
    float gz = z / (1.f + expf(-z));
    float val = fmaf(Dh, xh, ys) * gz;
    v[i] = val;
    acc = fmaf(val, val, acc);
  }
  #pragma unroll
  for (int off = 32; off; off >>= 1) acc += __shfl_xor(acc, off);
  __shared__ float wsum[4];
  if ((tid & 63) == 0) wsum[tid >> 6] = acc;
  __syncthreads();
  float total = wsum[0] + wsum[1] + wsum[2] + wsum[3];
  float scale = rsqrtf(total / (float)D_INNER + 1e-5f);
  #pragma unroll
  for (int i = 0; i < 8; ++i) {
    int d = i * 256 + tid;
    y[(size_t)row * D_INNER + d] = v[i] * scale * norm_w[d];
  }
}

// ---------------------------------------------------------------------------
// LayerNorm + residual
// ---------------------------------------------------------------------------
__global__ __launch_bounds__(256) void ln_kernel(
    const float* __restrict__ o, const float* __restrict__ x,
    const float* __restrict__ lng, const float* __restrict__ lnb,
    float* __restrict__ out) {
  const int row = blockIdx.x;
  const int tid = threadIdx.x;
  float v[4];
  float s = 0.f, s2 = 0.f;
  #pragma unroll
  for (int i = 0; i < 4; ++i) {
    int d = i * 256 + tid;
    float t = o[(size_t)row * D_MODEL + d];
    v[i] = t;
    s += t;
    s2 = fmaf(t, t, s2);
  }
  #pragma unroll
  for (int off = 32; off; off >>= 1) {
    s  += __shfl_xor(s, off);
    s2 += __shfl_xor(s2, off);
  }
  __shared__ float sa[4], sb[4];
  if ((tid & 63) == 0) { sa[tid >> 6] = s; sb[tid >> 6] = s2; }
  __syncthreads();
  s  = sa[0] + sa[1] + sa[2] + sa[3];
  s2 = sb[0] + sb[1] + sb[2] + sb[3];
  float mu  = s / (float)D_MODEL;
  float var = s2 / (float)D_MODEL - mu * mu;
  float inv = rsqrtf(var + 1e-5f);
  #pragma unroll
  for (int i = 0; i < 4; ++i) {
    int d = i * 256 + tid;
    out[(size_t)row * D_MODEL + d] =
        (v[i] - mu) * inv * lng[d] + lnb[d] + x[(size_t)row * D_MODEL + d];
  }
}

// ---------------------------------------------------------------------------
extern "C" void kernel_launch(void* const* d_in, const int* in_sizes, int n_in,
                              void* d_out, int out_size, void* d_ws, size_t ws_size,
                              hipStream_t stream) {
  const float* x         = (const float*)d_in[0];
  const float* in_proj_w = (const float*)d_in[1];
  const float* conv_w    = (const float*)d_in[2];
  const float* conv_b    = (const float*)d_in[3];
  const float* dt_bias   = (const float*)d_in[4];
  const float* A_log     = (const float*)d_in[5];
  const float* D_skip    = (const float*)d_in[6];
  const float* norm_w    = (const float*)d_in[7];
  const float* out_w     = (const float*)d_in[8];
  const float* ln_g      = (const float*)d_in[9];
  const float* ln_b      = (const float*)d_in[10];
  float* out = (float*)d_out;

  float* ws      = (float*)d_ws;
  float* zxbcdt  = ws;                                    // NROWS * D_IN_PROJ
  float* xconv   = zxbcdt + (size_t)NROWS * D_IN_PROJ;    // NROWS * CONV_DIM
  float* dt_s    = xconv + (size_t)NROWS * CONV_DIM;      // NROWS * NHEADS
  float* cumL    = dt_s + (size_t)NROWS * NHEADS;         // BATCH*NC*NHEADS*64
  float* ybuf    = cumL + (size_t)BATCH * NC * NHEADS * 64; // NROWS * D_INNER
  float* outpre  = zxbcdt;   // reuse after gate_rms

  // 1. in_proj GEMM
  gemm_nt<<<dim3((D_IN_PROJ + BN - 1) / BN, NROWS / BM), dim3(256), 0, stream>>>(
      x, in_proj_w, zxbcdt, NROWS, D_IN_PROJ, D_MODEL);

  // 2. conv + silu
  conv_silu_kernel<<<dim3(CONV_DIM / 256, LSEQ, BATCH), dim3(256), 0, stream>>>(
      zxbcdt, conv_w, conv_b, xconv);

  // 3. dt
  dt_kernel<<<dim3(NROWS * NHEADS / 256), dim3(256), 0, stream>>>(
      zxbcdt, dt_bias, dt_s);

  // 4. per-chunk cumsum
  cumsum_kernel<<<dim3(BATCH * NC * NHEADS / 4), dim3(256), 0, stream>>>(
      dt_s, A_log, cumL);

  // 5. inter-chunk (writes ybuf)
  inter_kernel<<<dim3(BATCH * NHEADS * 4), dim3(256), 0, stream>>>(
      xconv, dt_s, cumL, ybuf);

  // 6. intra-chunk (adds into ybuf)
  intra_kernel<<<dim3(BATCH * NC * NHEADS), dim3(256), 0, stream>>>(
      xconv, dt_s, cumL, ybuf);

  // 7. gate + rmsnorm
  gate_rms_kernel<<<dim3(NROWS), dim3(256), 0, stream>>>(
      ybuf, zxbcdt, xconv, D_skip, norm_w);

  // 8. out_proj GEMM
  gemm_nt<<<dim3(D_MODEL / BN, NROWS / BM), dim3(256), 0, stream>>>(
      ybuf, out_w, outpre, NROWS, D_MODEL, D_INNER);

  // 9. layernorm + residual
  ln_kernel<<<dim3(NROWS), dim3(256), 0, stream>>>(
      outpre, x, ln_g, ln_b, out);
}

// Round 3
// 1056.622 us; speedup vs baseline: 2.9154x; 2.9154x over previous
//
#include <hip/hip_runtime.h>
#include <math.h>

#define D_MODEL   1024
#define D_INNER   2048
#define HEADDIM   64
#define NHEADS    32
#define D_STATE   128
#define D_CONV    4
#define CONV_DIM  2304      // D_INNER + 2*D_STATE
#define D_IN_PROJ 4384      // 2*D_INNER + 2*D_STATE + NHEADS
#define LSEQ      2048
#define BATCH     2
#define NROWS     4096      // BATCH * LSEQ
#define NC        32        // chunks per batch (LSEQ / 64)

typedef __attribute__((ext_vector_type(8))) short short8_t;
typedef __attribute__((ext_vector_type(4))) float f32x4;

#define MFMA16(a, b, c) __builtin_amdgcn_mfma_f32_16x16x32_bf16(a, b, c, 0, 0, 0)

__device__ __forceinline__ unsigned short f2bf(float f) {
  union { float f; unsigned int u; } v; v.f = f;
  unsigned int u = v.u + 0x7FFFu + ((v.u >> 16) & 1u);
  return (unsigned short)(u >> 16);
}
__device__ __forceinline__ float bf2f(unsigned short h) {
  union { unsigned int u; float f; } v; v.u = ((unsigned int)h) << 16;
  return v.f;
}

// XOR-swizzled LDS helpers (bf16 storage, swizzle byte ^= (row&7)<<4)
__device__ __forceinline__ short8_t lds_frag(const unsigned short* base, int row,
                                             int col, int rowlen) {
  int off = (row * rowlen + col) * 2;
  off ^= (row & 7) << 4;
  return *reinterpret_cast<const short8_t*>(
      reinterpret_cast<const char*>(base) + off);
}
__device__ __forceinline__ void lds_w32(unsigned short* base, int row, int col,
                                        int rowlen, unsigned int val) {
  int off = (row * rowlen + col) * 2;
  off ^= (row & 7) << 4;
  *reinterpret_cast<unsigned int*>(reinterpret_cast<char*>(base) + off) = val;
}
__device__ __forceinline__ void lds_w16(unsigned short* base, int row, int col,
                                        int rowlen, unsigned short val) {
  int off = (row * rowlen + col) * 2;
  off ^= (row & 7) << 4;
  *reinterpret_cast<unsigned short*>(reinterpret_cast<char*>(base) + off) = val;
}
__device__ __forceinline__ unsigned short lds_r16(const unsigned short* base,
                                                  int row, int col, int rowlen) {
  int off = (row * rowlen + col) * 2;
  off ^= (row & 7) << 4;
  return *reinterpret_cast<const unsigned short*>(
      reinterpret_cast<const char*>(base) + off);
}

// ---------------------------------------------------------------------------
// fp32 GEMM (NT), unchanged from round 1
// ---------------------------------------------------------------------------
#define BM 128
#define BN 128
#define BK 16
#define LDP 132

__global__ __launch_bounds__(256) void gemm_nt(
    const float* __restrict__ A, const float* __restrict__ B,
    float* __restrict__ C, int M, int N, int K) {
  __shared__ __align__(16) float sA[BK][LDP];
  __shared__ __align__(16) float sB[BK][LDP];
  const int tid = threadIdx.x;
  const int row0 = blockIdx.y * BM;
  const int col0 = blockIdx.x * BN;
  const int tx = tid & 15;
  const int ty = tid >> 4;

  float acc[8][8] = {};

  for (int k0 = 0; k0 < K; k0 += BK) {
    #pragma unroll
    for (int i = 0; i < 2; ++i) {
      int f  = tid + i * 256;
      int m  = f >> 2;
      int kq = f & 3;
      {
        int gm = row0 + m;
        float4 v = make_float4(0.f, 0.f, 0.f, 0.f);
        if (gm < M)
          v = *reinterpret_cast<const float4*>(&A[(size_t)gm * K + k0 + kq * 4]);
        sA[kq * 4 + 0][m] = v.x; sA[kq * 4 + 1][m] = v.y;
        sA[kq * 4 + 2][m] = v.z; sA[kq * 4 + 3][m] = v.w;
      }
      {
        int gn = col0 + m;
        float4 v = make_float4(0.f, 0.f, 0.f, 0.f);
        if (gn < N)
          v = *reinterpret_cast<const float4*>(&B[(size_t)gn * K + k0 + kq * 4]);
        sB[kq * 4 + 0][m] = v.x; sB[kq * 4 + 1][m] = v.y;
        sB[kq * 4 + 2][m] = v.z; sB[kq * 4 + 3][m] = v.w;
      }
    }
    __syncthreads();

    #pragma unroll
    for (int kk = 0; kk < BK; ++kk) {
      float4 a0 = *reinterpret_cast<const float4*>(&sA[kk][ty * 8]);
      float4 a1 = *reinterpret_cast<const float4*>(&sA[kk][ty * 8 + 4]);
      float4 b0 = *reinterpret_cast<const float4*>(&sB[kk][tx * 4]);
      float4 b1 = *reinterpret_cast<const float4*>(&sB[kk][64 + tx * 4]);
      float a[8] = {a0.x, a0.y, a0.z, a0.w, a1.x, a1.y, a1.z, a1.w};
      float b[8] = {b0.x, b0.y, b0.z, b0.w, b1.x, b1.y, b1.z, b1.w};
      #pragma unroll
      for (int i = 0; i < 8; ++i)
        #pragma unroll
        for (int j = 0; j < 8; ++j)
          acc[i][j] = fmaf(a[i], b[j], acc[i][j]);
    }
    __syncthreads();
  }

  #pragma unroll
  for (int i = 0; i < 8; ++i) {
    int gm = row0 + ty * 8 + i;
    if (gm >= M) continue;
    #pragma unroll
    for (int j = 0; j < 8; ++j) {
      int cn = (j < 4) ? (tx * 4 + j) : (64 + tx * 4 + (j - 4));
      int gn = col0 + cn;
      if (gn < N) C[(size_t)gm * N + gn] = acc[i][j];
    }
  }
}

// ---------------------------------------------------------------------------
// depthwise causal conv (K=4) + bias + silu
// ---------------------------------------------------------------------------
__global__ __launch_bounds__(256) void conv_silu_kernel(
    const float* __restrict__ zxbcdt, const float* __restrict__ conv_w,
    const float* __restrict__ conv_b, float* __restrict__ xconv) {
  const int c = blockIdx.x * 256 + threadIdx.x;
  const int l = blockIdx.y;
  const int b = blockIdx.z;
  const float* src = zxbcdt + ((size_t)b * LSEQ) * D_IN_PROJ + D_INNER + c;
  float w0 = conv_w[c * 4 + 0], w1 = conv_w[c * 4 + 1];
  float w2 = conv_w[c * 4 + 2], w3 = conv_w[c * 4 + 3];
  float acc = conv_b[c];
  if (l >= 3) acc = fmaf(w0, src[(size_t)(l - 3) * D_IN_PROJ], acc);
  if (l >= 2) acc = fmaf(w1, src[(size_t)(l - 2) * D_IN_PROJ], acc);
  if (l >= 1) acc = fmaf(w2, src[(size_t)(l - 1) * D_IN_PROJ], acc);
  acc = fmaf(w3, src[(size_t)l * D_IN_PROJ], acc);
  float s = acc / (1.f + expf(-acc));
  xconv[((size_t)b * LSEQ + l) * CONV_DIM + c] = s;
}

// ---------------------------------------------------------------------------
// dt = softplus(dt_raw + dt_bias)
// ---------------------------------------------------------------------------
__global__ __launch_bounds__(256) void dt_kernel(
    const float* __restrict__ zxbcdt, const float* __restrict__ dt_bias,
    float* __restrict__ dt_out) {
  int idx = blockIdx.x * 256 + threadIdx.x;
  int h = idx & 31;
  int row = idx >> 5;
  float x = zxbcdt[(size_t)row * D_IN_PROJ + (D_INNER + CONV_DIM) + h] + dt_bias[h];
  float dt = (x > 20.f) ? x : log1pf(expf(x));
  dt_out[idx] = dt;
}

// ---------------------------------------------------------------------------
// per-chunk inclusive cumsum of a_t = dt_t * A_h.  one wave per (b,c,h).
// ---------------------------------------------------------------------------
__global__ __launch_bounds__(256) void cumsum_kernel(
    const float* __restrict__ dt_s, const float* __restrict__ A_log,
    float* __restrict__ cumL) {
  int u = blockIdx.x * 4 + (threadIdx.x >> 6);   // ((b*NC + c)*NHEADS + h)
  int lane = threadIdx.x & 63;
  int h = u & 31;
  int bc = u >> 5;
  int row = bc * 64 + lane;
  float A = -expf(A_log[h]);
  float a = dt_s[(size_t)row * NHEADS + h] * A;
  #pragma unroll
  for (int off = 1; off < 64; off <<= 1) {
    float v = __shfl_up(a, off);
    if (lane >= off) a += v;
  }
  cumL[(size_t)u * 64 + lane] = a;
}

// ---------------------------------------------------------------------------
// chunk state: S^T[p][n] = sum_s w_s x[s][p] B[s][n],  w_s = dt_s*exp(L63-L_s)
// one WG (256 thr) per (b,c,h) = 2048 WGs.  MFMA 16x16x32 bf16, K=64.
// S written bf16 [bi][p][n], bi = (b*NC+c)*NHEADS+h.
// ---------------------------------------------------------------------------
__global__ __launch_bounds__(256) void chunkstate_kernel(
    const float* __restrict__ xconv, const float* __restrict__ dt_s,
    const float* __restrict__ cumL, unsigned short* __restrict__ S) {
  const int bi = blockIdx.x;
  const int h  = bi & 31;
  const int bc = bi >> 5;
  const int row0 = bc * 64;
  const int tid = threadIdx.x;

  __shared__ unsigned short sBT[128 * 64];   // [n][s]
  __shared__ unsigned short sXT[64 * 64];    // [p][s]  (w-weighted)
  __shared__ float sw[64];

  if (tid < 64) {
    float L   = cumL[(size_t)bi * 64 + tid];
    float L63 = cumL[(size_t)bi * 64 + 63];
    sw[tid] = dt_s[(size_t)(row0 + tid) * NHEADS + h] * expf(L63 - L);
  }
  __syncthreads();

  // stage BT (transpose B) — read coalesced along n as float2
  #pragma unroll
  for (int i = 0; i < 16; ++i) {
    int idx = tid + i * 256;       // 0..4095
    int s = idx >> 6, n2 = idx & 63;
    float2 v = *reinterpret_cast<const float2*>(
        &xconv[(size_t)(row0 + s) * CONV_DIM + D_INNER + n2 * 2]);
    lds_w16(sBT, n2 * 2 + 0, s, 64, f2bf(v.x));
    lds_w16(sBT, n2 * 2 + 1, s, 64, f2bf(v.y));
  }
  // stage XTw (transpose x, weighted)
  #pragma unroll
  for (int i = 0; i < 16; ++i) {
    int idx = tid + i * 256;
    int s = idx >> 6, p = idx & 63;
    float xv = xconv[(size_t)(row0 + s) * CONV_DIM + h * HEADDIM + p];
    lds_w16(sXT, p, s, 64, f2bf(xv * sw[s]));
  }
  __syncthreads();

  const int w  = tid >> 6;
  const int l  = tid & 63;
  const int la = l & 15;
  const int lk = (l >> 4) * 8;

  f32x4 acc[8];
  #pragma unroll
  for (int i = 0; i < 8; ++i) acc[i] = (f32x4){0.f, 0.f, 0.f, 0.f};

  #pragma unroll
  for (int ks = 0; ks < 2; ++ks) {
    short8_t a = lds_frag(sXT, 16 * w + la, ks * 32 + lk, 64);
    #pragma unroll
    for (int ni = 0; ni < 8; ++ni) {
      short8_t b = lds_frag(sBT, ni * 16 + la, ks * 32 + lk, 64);
      acc[ni] = MFMA16(a, b, acc[ni]);
    }
  }

  unsigned short* dst = S + (size_t)bi * (HEADDIM * D_STATE);
  #pragma unroll
  for (int ni = 0; ni < 8; ++ni)
    #pragma unroll
    for (int r = 0; r < 4; ++r) {
      int p = 16 * w + (l >> 4) * 4 + r;
      int n = ni * 16 + la;
      dst[p * D_STATE + n] = f2bf(acc[ni][r]);
    }
}

// ---------------------------------------------------------------------------
// H recurrence, elementwise over (b,h,p,n); 32 sequential chunks.
// In place: S[bi] is replaced by Hprev[bi] (state BEFORE chunk c).
// ---------------------------------------------------------------------------
__global__ __launch_bounds__(256) void hscan_kernel(
    unsigned short* __restrict__ S, const float* __restrict__ cumL) {
  const int g  = blockIdx.x;           // 2048 WGs
  const int bh = g >> 5;               // b*NHEADS + h
  const int b  = bh >> 5;
  const int h  = bh & 31;
  const int e  = (g & 31) * 256 + threadIdx.x;   // 0..8191 = p*128+n

  float H = 0.f;
  #pragma unroll 4
  for (int c = 0; c < NC; ++c) {
    size_t u = (size_t)((b * NC + c) * NHEADS + h);
    float dA = expf(cumL[u * 64 + 63]);
    unsigned short sv = S[u * (HEADDIM * D_STATE) + e];
    S[u * (HEADDIM * D_STATE) + e] = f2bf(H);
    H = dA * H + bf2f(sv);
  }
}

// ---------------------------------------------------------------------------
// fused chunk kernel: per (b,c,h)
//   G = C·B^T (K=128) -> mask/decay -> P (bf16, LDS)
//   Y = eL∘(C·Hprev^T) + P·X + D_skip*x   -> ybuf
// ---------------------------------------------------------------------------
__global__ __launch_bounds__(256) void chunk_kernel(
    const float* __restrict__ xconv, const float* __restrict__ dt_s,
    const float* __restrict__ cumL, const unsigned short* __restrict__ Hprev,
    const float* __restrict__ D_skip, float* __restrict__ y) {
  const int bi = blockIdx.x;
  const int h  = bi & 31;
  const int bc = bi >> 5;
  const int row0 = bc * 64;
  const int tid = threadIdx.x;

  __shared__ unsigned short sC[64 * 128];
  __shared__ unsigned short sB[64 * 128];
  __shared__ unsigned short sXT[64 * 64];   // [p][s]
  __shared__ unsigned short sP[64 * 64];    // [t][s]
  __shared__ float sL[64], sdt[64], seL[64];

  if (tid < 64) {
    float L = cumL[(size_t)bi * 64 + tid];
    sL[tid]  = L;
    seL[tid] = expf(L);
    sdt[tid] = dt_s[(size_t)(row0 + tid) * NHEADS + h];
  }

  // stage B (n 0..127) and C (n 128..255) as bf16
  #pragma unroll
  for (int i = 0; i < 16; ++i) {
    int idx = tid + i * 256;       // 0..4095 float4 slots
    int r = idx >> 6, q = idx & 63;
    float4 v = *reinterpret_cast<const float4*>(
        &xconv[(size_t)(row0 + r) * CONV_DIM + D_INNER + q * 4]);
    unsigned int u0 = (unsigned int)f2bf(v.x) | ((unsigned int)f2bf(v.y) << 16);
    unsigned int u1 = (unsigned int)f2bf(v.z) | ((unsigned int)f2bf(v.w) << 16);
    if (q < 32) {
      lds_w32(sB, r, q * 4 + 0, 128, u0);
      lds_w32(sB, r, q * 4 + 2, 128, u1);
    } else {
      lds_w32(sC, r, (q - 32) * 4 + 0, 128, u0);
      lds_w32(sC, r, (q - 32) * 4 + 2, 128, u1);
    }
  }
  // stage x transposed
  #pragma unroll
  for (int i = 0; i < 16; ++i) {
    int idx = tid + i * 256;
    int s = idx >> 6, p = idx & 63;
    float xv = xconv[(size_t)(row0 + s) * CONV_DIM + h * HEADDIM + p];
    lds_w16(sXT, p, s, 64, f2bf(xv));
  }
  __syncthreads();

  const int w  = tid >> 6;
  const int l  = tid & 63;
  const int la = l & 15;
  const int lk = (l >> 4) * 8;
  const int t0 = 16 * w;

  // ---- G = C·B^T ----
  f32x4 g[4];
  #pragma unroll
  for (int i = 0; i < 4; ++i) g[i] = (f32x4){0.f, 0.f, 0.f, 0.f};
  #pragma unroll
  for (int ks = 0; ks < 4; ++ks) {
    short8_t a = lds_frag(sC, t0 + la, ks * 32 + lk, 128);
    #pragma unroll
    for (int si = 0; si < 4; ++si) {
      short8_t b = lds_frag(sB, si * 16 + la, ks * 32 + lk, 128);
      g[si] = MFMA16(a, b, g[si]);
    }
  }
  // ---- mask / decay -> P ----
  #pragma unroll
  for (int si = 0; si < 4; ++si)
    #pragma unroll
    for (int r = 0; r < 4; ++r) {
      int t = t0 + (l >> 4) * 4 + r;
      int s = si * 16 + la;
      float m = 0.f;
      if (s <= t) m = expf(sL[t] - sL[s]) * sdt[s] * g[si][r];
      lds_w16(sP, t, s, 64, f2bf(m));
    }
  __syncthreads();

  // ---- Y = eL∘(C·Hprev^T) + P·X ----
  f32x4 o[4];
  #pragma unroll
  for (int i = 0; i < 4; ++i) o[i] = (f32x4){0.f, 0.f, 0.f, 0.f};

  const unsigned short* hb = Hprev + (size_t)bi * (HEADDIM * D_STATE);
  #pragma unroll
  for (int ks = 0; ks < 4; ++ks) {
    short8_t a = lds_frag(sC, t0 + la, ks * 32 + lk, 128);
    #pragma unroll
    for (int si = 0; si < 4; ++si) {
      int p = si * 16 + la;
      short8_t b = *reinterpret_cast<const short8_t*>(
          &hb[p * D_STATE + ks * 32 + lk]);
      o[si] = MFMA16(a, b, o[si]);
    }
  }
  #pragma unroll
  for (int si = 0; si < 4; ++si)
    #pragma unroll
    for (int r = 0; r < 4; ++r) {
      int t = t0 + (l >> 4) * 4 + r;
      o[si][r] *= seL[t];
    }
  #pragma unroll
  for (int ks = 0; ks < 2; ++ks) {
    short8_t a = lds_frag(sP, t0 + la, ks * 32 + lk, 64);
    #pragma unroll
    for (int si = 0; si < 4; ++si) {
      short8_t b = lds_frag(sXT, si * 16 + la, ks * 32 + lk, 64);
      o[si] = MFMA16(a, b, o[si]);
    }
  }
  // ---- + D_skip*x, write ----
  const float Dh = D_skip[h];
  #pragma unroll
  for (int si = 0; si < 4; ++si)
    #pragma unroll
    for (int r = 0; r < 4; ++r) {
      int t = t0 + (l >> 4) * 4 + r;
      int p = si * 16 + la;
      float xv = bf2f(lds_r16(sXT, p, t, 64));
      y[(size_t)(row0 + t) * D_INNER + h * HEADDIM + p] = o[si][r] + Dh * xv;
    }
}

// ---------------------------------------------------------------------------
// y = y * silu(z);  RMSNorm   (D_skip*xh already folded into chunk_kernel)
// ---------------------------------------------------------------------------
__global__ __launch_bounds__(256) void gate_rms_kernel(
    float* __restrict__ y, const float* __restrict__ zxbcdt,
    const float* __restrict__ norm_w) {
  const int row = blockIdx.x;
  const int tid = threadIdx.x;
  float v[8];
  float acc = 0.f;
  #pragma unroll
  for (int i = 0; i < 8; ++i) {
    int d = i * 256 + tid;
    float ys = y[(size_t)row * D_INNER + d];
    float z  = zxbcdt[(size_t)row * D_IN_PROJ + d];
    float gz = z / (1.f + expf(-z));
    float val = ys * gz;
    v[i] = val;
    acc = fmaf(val, val, acc);
  }
  #pragma unroll
  for (int off = 32; off; off >>= 1) acc += __shfl_xor(acc, off);
  __shared__ float wsum[4];
  if ((tid & 63) == 0) wsum[tid >> 6] = acc;
  __syncthreads();
  float total = wsum[0] + wsum[1] + wsum[2] + wsum[3];
  float scale = rsqrtf(total / (float)D_INNER + 1e-5f);
  #pragma unroll
  for (int i = 0; i < 8; ++i) {
    int d = i * 256 + tid;
    y[(size_t)row * D_INNER + d] = v[i] * scale * norm_w[d];
  }
}

// ---------------------------------------------------------------------------
// LayerNorm + residual
// ---------------------------------------------------------------------------
__global__ __launch_bounds__(256) void ln_kernel(
    const float* __restrict__ o, const float* __restrict__ x,
    const float* __restrict__ lng, const float* __restrict__ lnb,
    float* __restrict__ out) {
  const int row = blockIdx.x;
  const int tid = threadIdx.x;
  float v[4];
  float s = 0.f, s2 = 0.f;
  #pragma unroll
  for (int i = 0; i < 4; ++i) {
    int d = i * 256 + tid;
    float t = o[(size_t)row * D_MODEL + d];
    v[i] = t;
    s += t;
    s2 = fmaf(t, t, s2);
  }
  #pragma unroll
  for (int off = 32; off; off >>= 1) {
    s  += __shfl_xor(s, off);
    s2 += __shfl_xor(s2, off);
  }
  __shared__ float sa[4], sb[4];
  if ((tid & 63) == 0) { sa[tid >> 6] = s; sb[tid >> 6] = s2; }
  __syncthreads();
  s  = sa[0] + sa[1] + sa[2] + sa[3];
  s2 = sb[0] + sb[1] + sb[2] + sb[3];
  float mu  = s / (float)D_MODEL;
  float var = s2 / (float)D_MODEL - mu * mu;
  float inv = rsqrtf(var + 1e-5f);
  #pragma unroll
  for (int i = 0; i < 4; ++i) {
    int d = i * 256 + tid;
    out[(size_t)row * D_MODEL + d] =
        (v[i] - mu) * inv * lng[d] + lnb[d] + x[(size_t)row * D_MODEL + d];
  }
}

// ---------------------------------------------------------------------------
extern "C" void kernel_launch(void* const* d_in, const int* in_sizes, int n_in,
                              void* d_out, int out_size, void* d_ws, size_t ws_size,
                              hipStream_t stream) {
  const float* x         = (const float*)d_in[0];
  const float* in_proj_w = (const float*)d_in[1];
  const float* conv_w    = (const float*)d_in[2];
  const float* conv_b    = (const float*)d_in[3];
  const float* dt_bias   = (const float*)d_in[4];
  const float* A_log     = (const float*)d_in[5];
  const float* D_skip    = (const float*)d_in[6];
  const float* norm_w    = (const float*)d_in[7];
  const float* out_w     = (const float*)d_in[8];
  const float* ln_g      = (const float*)d_in[9];
  const float* ln_b      = (const float*)d_in[10];
  float* out = (float*)d_out;

  float* ws      = (float*)d_ws;
  float* zxbcdt  = ws;                                      // 4096*4384
  float* xconv   = zxbcdt + (size_t)NROWS * D_IN_PROJ;      // 4096*2304
  float* dt_s    = xconv + (size_t)NROWS * CONV_DIM;        // 4096*32
  float* cumL    = dt_s + (size_t)NROWS * NHEADS;           // 2048*64
  float* ybuf    = cumL + (size_t)BATCH * NC * NHEADS * 64; // 4096*2048
  unsigned short* schp = (unsigned short*)(ybuf + (size_t)NROWS * D_INNER);
  float* outpre  = zxbcdt;   // reuse after gate_rms consumed z

  // 1. in_proj GEMM
  gemm_nt<<<dim3((D_IN_PROJ + BN - 1) / BN, NROWS / BM), dim3(256), 0, stream>>>(
      x, in_proj_w, zxbcdt, NROWS, D_IN_PROJ, D_MODEL);

  // 2. conv + silu
  conv_silu_kernel<<<dim3(CONV_DIM / 256, LSEQ, BATCH), dim3(256), 0, stream>>>(
      zxbcdt, conv_w, conv_b, xconv);

  // 3. dt
  dt_kernel<<<dim3(NROWS * NHEADS / 256), dim3(256), 0, stream>>>(
      zxbcdt, dt_bias, dt_s);

  // 4. per-chunk cumsum
  cumsum_kernel<<<dim3(BATCH * NC * NHEADS / 4), dim3(256), 0, stream>>>(
      dt_s, A_log, cumL);

  // 5. chunk states S (bf16)
  chunkstate_kernel<<<dim3(BATCH * NC * NHEADS), dim3(256), 0, stream>>>(
      xconv, dt_s, cumL, schp);

  // 6. H recurrence (in place S -> Hprev)
  hscan_kernel<<<dim3(BATCH * NHEADS * 32), dim3(256), 0, stream>>>(
      schp, cumL);

  // 7. fused chunk kernel (writes ybuf)
  chunk_kernel<<<dim3(BATCH * NC * NHEADS), dim3(256), 0, stream>>>(
      xconv, dt_s, cumL, schp, D_skip, ybuf);

  // 8. gate + rmsnorm
  gate_rms_kernel<<<dim3(NROWS), dim3(256), 0, stream>>>(
      ybuf, zxbcdt, norm_w);

  // 9. out_proj GEMM
  gemm_nt<<<dim3(D_MODEL / BN, NROWS / BM), dim3(256), 0, stream>>>(
      ybuf, out_w, outpre, NROWS, D_MODEL, D_INNER);

  // 10. layernorm + residual
  ln_kernel<<<dim3(NROWS), dim3(256), 0, stream>>>(
      outpre, x, ln_g, ln_b, out);
}

// Round 4
// 351.916 us; speedup vs baseline: 8.7534x; 3.0025x over previous
//
#include <hip/hip_runtime.h>
#include <math.h>

#define D_MODEL   1024
#define D_INNER   2048
#define HEADDIM   64
#define NHEADS    32
#define D_STATE   128
#define D_CONV    4
#define CONV_DIM  2304      // D_INNER + 2*D_STATE
#define D_IN_PROJ 4384      // 2*D_INNER + 2*D_STATE + NHEADS
#define NPAD      4480      // D_IN_PROJ padded to multiple of 128
#define LSEQ      2048
#define BATCH     2
#define NROWS     4096      // BATCH * LSEQ
#define NC        32        // chunks per batch (LSEQ / 64)

typedef __attribute__((ext_vector_type(8))) short short8_t;
typedef __attribute__((ext_vector_type(4))) float f32x4;

#define MFMA16(a, b, c) __builtin_amdgcn_mfma_f32_16x16x32_bf16(a, b, c, 0, 0, 0)

// async global->LDS, 16B per lane (dest is wave-uniform base + lane*16)
#define GLDS(g, l) __builtin_amdgcn_global_load_lds( \
    (const __attribute__((address_space(1))) unsigned int*)(g), \
    (__attribute__((address_space(3))) unsigned int*)(l), 16, 0, 0)

__device__ __forceinline__ unsigned short f2bf(float f) {
  union { float f; unsigned int u; } v; v.f = f;
  unsigned int u = v.u + 0x7FFFu + ((v.u >> 16) & 1u);
  return (unsigned short)(u >> 16);
}
__device__ __forceinline__ float bf2f(unsigned short h) {
  union { unsigned int u; float f; } v; v.u = ((unsigned int)h) << 16;
  return v.f;
}

// XOR-swizzled LDS helpers (bf16 storage, swizzle byte ^= (row&7)<<4)
__device__ __forceinline__ short8_t lds_frag(const unsigned short* base, int row,
                                             int col, int rowlen) {
  int off = (row * rowlen + col) * 2;
  off ^= (row & 7) << 4;
  return *reinterpret_cast<const short8_t*>(
      reinterpret_cast<const char*>(base) + off);
}
__device__ __forceinline__ void lds_w32(unsigned short* base, int row, int col,
                                        int rowlen, unsigned int val) {
  int off = (row * rowlen + col) * 2;
  off ^= (row & 7) << 4;
  *reinterpret_cast<unsigned int*>(reinterpret_cast<char*>(base) + off) = val;
}
__device__ __forceinline__ void lds_w16(unsigned short* base, int row, int col,
                                        int rowlen, unsigned short val) {
  int off = (row * rowlen + col) * 2;
  off ^= (row & 7) << 4;
  *reinterpret_cast<unsigned short*>(reinterpret_cast<char*>(base) + off) = val;
}
__device__ __forceinline__ unsigned short lds_r16(const unsigned short* base,
                                                  int row, int col, int rowlen) {
  int off = (row * rowlen + col) * 2;
  off ^= (row & 7) << 4;
  return *reinterpret_cast<const unsigned short*>(
      reinterpret_cast<const char*>(base) + off);
}

// ---------------------------------------------------------------------------
// bf16 MFMA GEMM (NT): C[m][n] = sum_k A[m][k]*B[n][k], fp32 out.
// 128x128 tile, BK=64, 4 waves (2x2), 4x4 fragment grid per wave.
// global_load_lds w/ pre-swizzled source block (j ^ (row&7)); swizzled reads.
// Np = padded row count of B (loads unguarded); stores guarded by gn < N.
// ---------------------------------------------------------------------------
__global__ __launch_bounds__(256) void gemm_bf16(
    const unsigned short* __restrict__ A, const unsigned short* __restrict__ B,
    float* __restrict__ C, int N, int K) {
  __shared__ unsigned short sA[128 * 64];
  __shared__ unsigned short sB[128 * 64];
  const int tid = threadIdx.x;
  const int row0 = blockIdx.y * 128;
  const int col0 = blockIdx.x * 128;
  const int l  = tid & 63;
  const int la = l & 15;
  const int lk = (l >> 4) * 8;
  const int w  = tid >> 6;
  const int wr = (w >> 1) * 64;
  const int wc = (w & 1) * 64;

  f32x4 acc[4][4];
  #pragma unroll
  for (int i = 0; i < 4; ++i)
    #pragma unroll
    for (int j = 0; j < 4; ++j) acc[i][j] = (f32x4){0.f, 0.f, 0.f, 0.f};

  for (int k0 = 0; k0 < K; k0 += 64) {
    __syncthreads();
    #pragma unroll
    for (int i = 0; i < 4; ++i) {
      int s = i * 256 + tid;       // 0..1023 16B slots
      int r = s >> 3;              // tile row 0..127
      int j = s & 7;               // 16B block within row
      int jc = j ^ (r & 7);        // inverse-swizzled source block
      GLDS(&A[(size_t)(row0 + r) * K + k0 + jc * 8], &sA[s * 8]);
      GLDS(&B[(size_t)(col0 + r) * K + k0 + jc * 8], &sB[s * 8]);
    }
    __syncthreads();

    #pragma unroll
    for (int kk = 0; kk < 2; ++kk) {
      short8_t af[4], bfr[4];
      #pragma unroll
      for (int mi = 0; mi < 4; ++mi)
        af[mi] = lds_frag(sA, wr + mi * 16 + la, kk * 32 + lk, 64);
      #pragma unroll
      for (int ni = 0; ni < 4; ++ni)
        bfr[ni] = lds_frag(sB, wc + ni * 16 + la, kk * 32 + lk, 64);
      #pragma unroll
      for (int mi = 0; mi < 4; ++mi)
        #pragma unroll
        for (int ni = 0; ni < 4; ++ni)
          acc[mi][ni] = MFMA16(af[mi], bfr[ni], acc[mi][ni]);
    }
  }

  #pragma unroll
  for (int mi = 0; mi < 4; ++mi)
    #pragma unroll
    for (int ni = 0; ni < 4; ++ni)
      #pragma unroll
      for (int r = 0; r < 4; ++r) {
        int gm = row0 + wr + mi * 16 + (l >> 4) * 4 + r;
        int gn = col0 + wc + ni * 16 + la;
        if (gn < N) C[(size_t)gm * N + gn] = acc[mi][ni][r];
      }
}

// ---------------------------------------------------------------------------
// fp32 -> bf16 converts
// ---------------------------------------------------------------------------
__global__ __launch_bounds__(256) void cvt_bf16_kernel(
    const float* __restrict__ src, unsigned short* __restrict__ dst) {
  long i = (long)blockIdx.x * 256 + threadIdx.x;
  float4 a = *reinterpret_cast<const float4*>(&src[i * 8]);
  float4 b = *reinterpret_cast<const float4*>(&src[i * 8 + 4]);
  short8_t o;
  o[0] = (short)f2bf(a.x); o[1] = (short)f2bf(a.y);
  o[2] = (short)f2bf(a.z); o[3] = (short)f2bf(a.w);
  o[4] = (short)f2bf(b.x); o[5] = (short)f2bf(b.y);
  o[6] = (short)f2bf(b.z); o[7] = (short)f2bf(b.w);
  *reinterpret_cast<short8_t*>(&dst[i * 8]) = o;
}

// in_proj_w (4384 x 1024) -> bf16 padded to 4480 rows (zeros)
__global__ __launch_bounds__(256) void cvt_w_kernel(
    const float* __restrict__ w, unsigned short* __restrict__ wbf) {
  long i = (long)blockIdx.x * 256 + threadIdx.x;   // over NPAD*128
  int row = (int)(i >> 7);
  int c8  = (int)(i & 127) << 3;
  short8_t o = {0, 0, 0, 0, 0, 0, 0, 0};
  if (row < D_IN_PROJ) {
    float4 a = *reinterpret_cast<const float4*>(&w[(size_t)row * D_MODEL + c8]);
    float4 b = *reinterpret_cast<const float4*>(&w[(size_t)row * D_MODEL + c8 + 4]);
    o[0] = (short)f2bf(a.x); o[1] = (short)f2bf(a.y);
    o[2] = (short)f2bf(a.z); o[3] = (short)f2bf(a.w);
    o[4] = (short)f2bf(b.x); o[5] = (short)f2bf(b.y);
    o[6] = (short)f2bf(b.z); o[7] = (short)f2bf(b.w);
  }
  *reinterpret_cast<short8_t*>(&wbf[(size_t)row * D_MODEL + c8]) = o;
}

// ---------------------------------------------------------------------------
// depthwise causal conv (K=4) + bias + silu
// ---------------------------------------------------------------------------
__global__ __launch_bounds__(256) void conv_silu_kernel(
    const float* __restrict__ zxbcdt, const float* __restrict__ conv_w,
    const float* __restrict__ conv_b, float* __restrict__ xconv) {
  const int c = blockIdx.x * 256 + threadIdx.x;
  const int l = blockIdx.y;
  const int b = blockIdx.z;
  const float* src = zxbcdt + ((size_t)b * LSEQ) * D_IN_PROJ + D_INNER + c;
  float w0 = conv_w[c * 4 + 0], w1 = conv_w[c * 4 + 1];
  float w2 = conv_w[c * 4 + 2], w3 = conv_w[c * 4 + 3];
  float acc = conv_b[c];
  if (l >= 3) acc = fmaf(w0, src[(size_t)(l - 3) * D_IN_PROJ], acc);
  if (l >= 2) acc = fmaf(w1, src[(size_t)(l - 2) * D_IN_PROJ], acc);
  if (l >= 1) acc = fmaf(w2, src[(size_t)(l - 1) * D_IN_PROJ], acc);
  acc = fmaf(w3, src[(size_t)l * D_IN_PROJ], acc);
  float s = acc / (1.f + expf(-acc));
  xconv[((size_t)b * LSEQ + l) * CONV_DIM + c] = s;
}

// ---------------------------------------------------------------------------
// dt = softplus(dt_raw + dt_bias)
// ---------------------------------------------------------------------------
__global__ __launch_bounds__(256) void dt_kernel(
    const float* __restrict__ zxbcdt, const float* __restrict__ dt_bias,
    float* __restrict__ dt_out) {
  int idx = blockIdx.x * 256 + threadIdx.x;
  int h = idx & 31;
  int row = idx >> 5;
  float x = zxbcdt[(size_t)row * D_IN_PROJ + (D_INNER + CONV_DIM) + h] + dt_bias[h];
  float dt = (x > 20.f) ? x : log1pf(expf(x));
  dt_out[idx] = dt;
}

// ---------------------------------------------------------------------------
// per-chunk inclusive cumsum of a_t = dt_t * A_h.  one wave per (b,c,h).
// ---------------------------------------------------------------------------
__global__ __launch_bounds__(256) void cumsum_kernel(
    const float* __restrict__ dt_s, const float* __restrict__ A_log,
    float* __restrict__ cumL) {
  int u = blockIdx.x * 4 + (threadIdx.x >> 6);
  int lane = threadIdx.x & 63;
  int h = u & 31;
  int bc = u >> 5;
  int row = bc * 64 + lane;
  float A = -expf(A_log[h]);
  float a = dt_s[(size_t)row * NHEADS + h] * A;
  #pragma unroll
  for (int off = 1; off < 64; off <<= 1) {
    float v = __shfl_up(a, off);
    if (lane >= off) a += v;
  }
  cumL[(size_t)u * 64 + lane] = a;
}

// ---------------------------------------------------------------------------
// chunk state: S^T[p][n] = sum_s w_s x[s][p] B[s][n]
// ---------------------------------------------------------------------------
__global__ __launch_bounds__(256) void chunkstate_kernel(
    const float* __restrict__ xconv, const float* __restrict__ dt_s,
    const float* __restrict__ cumL, unsigned short* __restrict__ S) {
  const int bi = blockIdx.x;
  const int h  = bi & 31;
  const int bc = bi >> 5;
  const int row0 = bc * 64;
  const int tid = threadIdx.x;

  __shared__ unsigned short sBT[128 * 64];   // [n][s]
  __shared__ unsigned short sXT[64 * 64];    // [p][s]  (w-weighted)
  __shared__ float sw[64];

  if (tid < 64) {
    float L   = cumL[(size_t)bi * 64 + tid];
    float L63 = cumL[(size_t)bi * 64 + 63];
    sw[tid] = dt_s[(size_t)(row0 + tid) * NHEADS + h] * expf(L63 - L);
  }
  __syncthreads();

  #pragma unroll
  for (int i = 0; i < 16; ++i) {
    int idx = tid + i * 256;
    int s = idx >> 6, n2 = idx & 63;
    float2 v = *reinterpret_cast<const float2*>(
        &xconv[(size_t)(row0 + s) * CONV_DIM + D_INNER + n2 * 2]);
    lds_w16(sBT, n2 * 2 + 0, s, 64, f2bf(v.x));
    lds_w16(sBT, n2 * 2 + 1, s, 64, f2bf(v.y));
  }
  #pragma unroll
  for (int i = 0; i < 16; ++i) {
    int idx = tid + i * 256;
    int s = idx >> 6, p = idx & 63;
    float xv = xconv[(size_t)(row0 + s) * CONV_DIM + h * HEADDIM + p];
    lds_w16(sXT, p, s, 64, f2bf(xv * sw[s]));
  }
  __syncthreads();

  const int w  = tid >> 6;
  const int l  = tid & 63;
  const int la = l & 15;
  const int lk = (l >> 4) * 8;

  f32x4 acc[8];
  #pragma unroll
  for (int i = 0; i < 8; ++i) acc[i] = (f32x4){0.f, 0.f, 0.f, 0.f};

  #pragma unroll
  for (int ks = 0; ks < 2; ++ks) {
    short8_t a = lds_frag(sXT, 16 * w + la, ks * 32 + lk, 64);
    #pragma unroll
    for (int ni = 0; ni < 8; ++ni) {
      short8_t b = lds_frag(sBT, ni * 16 + la, ks * 32 + lk, 64);
      acc[ni] = MFMA16(a, b, acc[ni]);
    }
  }

  unsigned short* dst = S + (size_t)bi * (HEADDIM * D_STATE);
  #pragma unroll
  for (int ni = 0; ni < 8; ++ni)
    #pragma unroll
    for (int r = 0; r < 4; ++r) {
      int p = 16 * w + (l >> 4) * 4 + r;
      int n = ni * 16 + la;
      dst[p * D_STATE + n] = f2bf(acc[ni][r]);
    }
}

// ---------------------------------------------------------------------------
// H recurrence, elementwise; in place S -> Hprev.
// ---------------------------------------------------------------------------
__global__ __launch_bounds__(256) void hscan_kernel(
    unsigned short* __restrict__ S, const float* __restrict__ cumL) {
  const int g  = blockIdx.x;
  const int bh = g >> 5;
  const int b  = bh >> 5;
  const int h  = bh & 31;
  const int e  = (g & 31) * 256 + threadIdx.x;

  float H = 0.f;
  #pragma unroll 4
  for (int c = 0; c < NC; ++c) {
    size_t u = (size_t)((b * NC + c) * NHEADS + h);
    float dA = expf(cumL[u * 64 + 63]);
    unsigned short sv = S[u * (HEADDIM * D_STATE) + e];
    S[u * (HEADDIM * D_STATE) + e] = f2bf(H);
    H = dA * H + bf2f(sv);
  }
}

// ---------------------------------------------------------------------------
// fused chunk kernel -> y (bf16)
// ---------------------------------------------------------------------------
__global__ __launch_bounds__(256) void chunk_kernel(
    const float* __restrict__ xconv, const float* __restrict__ dt_s,
    const float* __restrict__ cumL, const unsigned short* __restrict__ Hprev,
    const float* __restrict__ D_skip, unsigned short* __restrict__ y) {
  const int bi = blockIdx.x;
  const int h  = bi & 31;
  const int bc = bi >> 5;
  const int row0 = bc * 64;
  const int tid = threadIdx.x;

  __shared__ unsigned short sC[64 * 128];
  __shared__ unsigned short sB[64 * 128];
  __shared__ unsigned short sXT[64 * 64];
  __shared__ unsigned short sP[64 * 64];
  __shared__ float sL[64], sdt[64], seL[64];

  if (tid < 64) {
    float L = cumL[(size_t)bi * 64 + tid];
    sL[tid]  = L;
    seL[tid] = expf(L);
    sdt[tid] = dt_s[(size_t)(row0 + tid) * NHEADS + h];
  }

  #pragma unroll
  for (int i = 0; i < 16; ++i) {
    int idx = tid + i * 256;
    int r = idx >> 6, q = idx & 63;
    float4 v = *reinterpret_cast<const float4*>(
        &xconv[(size_t)(row0 + r) * CONV_DIM + D_INNER + q * 4]);
    unsigned int u0 = (unsigned int)f2bf(v.x) | ((unsigned int)f2bf(v.y) << 16);
    unsigned int u1 = (unsigned int)f2bf(v.z) | ((unsigned int)f2bf(v.w) << 16);
    if (q < 32) {
      lds_w32(sB, r, q * 4 + 0, 128, u0);
      lds_w32(sB, r, q * 4 + 2, 128, u1);
    } else {
      lds_w32(sC, r, (q - 32) * 4 + 0, 128, u0);
      lds_w32(sC, r, (q - 32) * 4 + 2, 128, u1);
    }
  }
  #pragma unroll
  for (int i = 0; i < 16; ++i) {
    int idx = tid + i * 256;
    int s = idx >> 6, p = idx & 63;
    float xv = xconv[(size_t)(row0 + s) * CONV_DIM + h * HEADDIM + p];
    lds_w16(sXT, p, s, 64, f2bf(xv));
  }
  __syncthreads();

  const int w  = tid >> 6;
  const int l  = tid & 63;
  const int la = l & 15;
  const int lk = (l >> 4) * 8;
  const int t0 = 16 * w;

  f32x4 g[4];
  #pragma unroll
  for (int i = 0; i < 4; ++i) g[i] = (f32x4){0.f, 0.f, 0.f, 0.f};
  #pragma unroll
  for (int ks = 0; ks < 4; ++ks) {
    short8_t a = lds_frag(sC, t0 + la, ks * 32 + lk, 128);
    #pragma unroll
    for (int si = 0; si < 4; ++si) {
      short8_t b = lds_frag(sB, si * 16 + la, ks * 32 + lk, 128);
      g[si] = MFMA16(a, b, g[si]);
    }
  }
  #pragma unroll
  for (int si = 0; si < 4; ++si)
    #pragma unroll
    for (int r = 0; r < 4; ++r) {
      int t = t0 + (l >> 4) * 4 + r;
      int s = si * 16 + la;
      float m = 0.f;
      if (s <= t) m = expf(sL[t] - sL[s]) * sdt[s] * g[si][r];
      lds_w16(sP, t, s, 64, f2bf(m));
    }
  __syncthreads();

  f32x4 o[4];
  #pragma unroll
  for (int i = 0; i < 4; ++i) o[i] = (f32x4){0.f, 0.f, 0.f, 0.f};

  const unsigned short* hb = Hprev + (size_t)bi * (HEADDIM * D_STATE);
  #pragma unroll
  for (int ks = 0; ks < 4; ++ks) {
    short8_t a = lds_frag(sC, t0 + la, ks * 32 + lk, 128);
    #pragma unroll
    for (int si = 0; si < 4; ++si) {
      int p = si * 16 + la;
      short8_t b = *reinterpret_cast<const short8_t*>(
          &hb[p * D_STATE + ks * 32 + lk]);
      o[si] = MFMA16(a, b, o[si]);
    }
  }
  #pragma unroll
  for (int si = 0; si < 4; ++si)
    #pragma unroll
    for (int r = 0; r < 4; ++r) {
      int t = t0 + (l >> 4) * 4 + r;
      o[si][r] *= seL[t];
    }
  #pragma unroll
  for (int ks = 0; ks < 2; ++ks) {
    short8_t a = lds_frag(sP, t0 + la, ks * 32 + lk, 64);
    #pragma unroll
    for (int si = 0; si < 4; ++si) {
      short8_t b = lds_frag(sXT, si * 16 + la, ks * 32 + lk, 64);
      o[si] = MFMA16(a, b, o[si]);
    }
  }
  const float Dh = D_skip[h];
  #pragma unroll
  for (int si = 0; si < 4; ++si)
    #pragma unroll
    for (int r = 0; r < 4; ++r) {
      int t = t0 + (l >> 4) * 4 + r;
      int p = si * 16 + la;
      float xv = bf2f(lds_r16(sXT, p, t, 64));
      y[(size_t)(row0 + t) * D_INNER + h * HEADDIM + p] = f2bf(o[si][r] + Dh * xv);
    }
}

// ---------------------------------------------------------------------------
// y(bf16) = y * silu(z); RMSNorm; in-place bf16
// ---------------------------------------------------------------------------
__global__ __launch_bounds__(256) void gate_rms_kernel(
    unsigned short* __restrict__ y, const float* __restrict__ zxbcdt,
    const float* __restrict__ norm_w) {
  const int row = blockIdx.x;
  const int tid = threadIdx.x;
  float v[8];
  float acc = 0.f;
  #pragma unroll
  for (int i = 0; i < 8; ++i) {
    int d = i * 256 + tid;
    float ys = bf2f(y[(size_t)row * D_INNER + d]);
    float z  = zxbcdt[(size_t)row * D_IN_PROJ + d];
    float gz = z / (1.f + expf(-z));
    float val = ys * gz;
    v[i] = val;
    acc = fmaf(val, val, acc);
  }
  #pragma unroll
  for (int off = 32; off; off >>= 1) acc += __shfl_xor(acc, off);
  __shared__ float wsum[4];
  if ((tid & 63) == 0) wsum[tid >> 6] = acc;
  __syncthreads();
  float total = wsum[0] + wsum[1] + wsum[2] + wsum[3];
  float scale = rsqrtf(total / (float)D_INNER + 1e-5f);
  #pragma unroll
  for (int i = 0; i < 8; ++i) {
    int d = i * 256 + tid;
    y[(size_t)row * D_INNER + d] = f2bf(v[i] * scale * norm_w[d]);
  }
}

// ---------------------------------------------------------------------------
// LayerNorm + residual
// ---------------------------------------------------------------------------
__global__ __launch_bounds__(256) void ln_kernel(
    const float* __restrict__ o, const float* __restrict__ x,
    const float* __restrict__ lng, const float* __restrict__ lnb,
    float* __restrict__ out) {
  const int row = blockIdx.x;
  const int tid = threadIdx.x;
  float v[4];
  float s = 0.f, s2 = 0.f;
  #pragma unroll
  for (int i = 0; i < 4; ++i) {
    int d = i * 256 + tid;
    float t = o[(size_t)row * D_MODEL + d];
    v[i] = t;
    s += t;
    s2 = fmaf(t, t, s2);
  }
  #pragma unroll
  for (int off = 32; off; off >>= 1) {
    s  += __shfl_xor(s, off);
    s2 += __shfl_xor(s2, off);
  }
  __shared__ float sa[4], sb[4];
  if ((tid & 63) == 0) { sa[tid >> 6] = s; sb[tid >> 6] = s2; }
  __syncthreads();
  s  = sa[0] + sa[1] + sa[2] + sa[3];
  s2 = sb[0] + sb[1] + sb[2] + sb[3];
  float mu  = s / (float)D_MODEL;
  float var = s2 / (float)D_MODEL - mu * mu;
  float inv = rsqrtf(var + 1e-5f);
  #pragma unroll
  for (int i = 0; i < 4; ++i) {
    int d = i * 256 + tid;
    out[(size_t)row * D_MODEL + d] =
        (v[i] - mu) * inv * lng[d] + lnb[d] + x[(size_t)row * D_MODEL + d];
  }
}

// ---------------------------------------------------------------------------
extern "C" void kernel_launch(void* const* d_in, const int* in_sizes, int n_in,
                              void* d_out, int out_size, void* d_ws, size_t ws_size,
                              hipStream_t stream) {
  const float* x         = (const float*)d_in[0];
  const float* in_proj_w = (const float*)d_in[1];
  const float* conv_w    = (const float*)d_in[2];
  const float* conv_b    = (const float*)d_in[3];
  const float* dt_bias   = (const float*)d_in[4];
  const float* A_log     = (const float*)d_in[5];
  const float* D_skip    = (const float*)d_in[6];
  const float* norm_w    = (const float*)d_in[7];
  const float* out_w     = (const float*)d_in[8];
  const float* ln_g      = (const float*)d_in[9];
  const float* ln_b      = (const float*)d_in[10];
  float* out = (float*)d_out;

  float* ws      = (float*)d_ws;
  float* zxbcdt  = ws;                                      // 4096*4384 f32
  float* xconv   = zxbcdt + (size_t)NROWS * D_IN_PROJ;      // 4096*2304 f32
  float* dt_s    = xconv + (size_t)NROWS * CONV_DIM;        // 4096*32
  float* cumL    = dt_s + (size_t)NROWS * NHEADS;           // 2048*64
  unsigned short* schp = (unsigned short*)(cumL + (size_t)BATCH * NC * NHEADS * 64);
  unsigned short* ybuf = schp + (size_t)BATCH * NC * NHEADS * HEADDIM * D_STATE;
  unsigned short* xbf  = ybuf + (size_t)NROWS * D_INNER;    // 4096*1024 bf16
  unsigned short* wbf  = xbf + (size_t)NROWS * D_MODEL;     // 4480*1024 bf16
  unsigned short* owbf = wbf + (size_t)NPAD * D_MODEL;      // 1024*2048 bf16
  float* outpre  = zxbcdt;   // reuse after gate_rms consumed z

  // 0. converts
  cvt_bf16_kernel<<<dim3(NROWS * D_MODEL / 8 / 256), dim3(256), 0, stream>>>(
      x, xbf);
  cvt_w_kernel<<<dim3(NPAD * 128 / 256), dim3(256), 0, stream>>>(
      in_proj_w, wbf);
  cvt_bf16_kernel<<<dim3(D_MODEL * D_INNER / 8 / 256), dim3(256), 0, stream>>>(
      out_w, owbf);

  // 1. in_proj GEMM (bf16 MFMA): 4096 x 4384 (pad 4480) x K=1024
  gemm_bf16<<<dim3(NPAD / 128, NROWS / 128), dim3(256), 0, stream>>>(
      xbf, wbf, zxbcdt, D_IN_PROJ, D_MODEL);

  // 2. conv + silu
  conv_silu_kernel<<<dim3(CONV_DIM / 256, LSEQ, BATCH), dim3(256), 0, stream>>>(
      zxbcdt, conv_w, conv_b, xconv);

  // 3. dt
  dt_kernel<<<dim3(NROWS * NHEADS / 256), dim3(256), 0, stream>>>(
      zxbcdt, dt_bias, dt_s);

  // 4. per-chunk cumsum
  cumsum_kernel<<<dim3(BATCH * NC * NHEADS / 4), dim3(256), 0, stream>>>(
      dt_s, A_log, cumL);

  // 5. chunk states S (bf16)
  chunkstate_kernel<<<dim3(BATCH * NC * NHEADS), dim3(256), 0, stream>>>(
      xconv, dt_s, cumL, schp);

  // 6. H recurrence (in place S -> Hprev)
  hscan_kernel<<<dim3(BATCH * NHEADS * 32), dim3(256), 0, stream>>>(
      schp, cumL);

  // 7. fused chunk kernel (writes ybuf bf16)
  chunk_kernel<<<dim3(BATCH * NC * NHEADS), dim3(256), 0, stream>>>(
      xconv, dt_s, cumL, schp, D_skip, ybuf);

  // 8. gate + rmsnorm (in-place bf16)
  gate_rms_kernel<<<dim3(NROWS), dim3(256), 0, stream>>>(
      ybuf, zxbcdt, norm_w);

  // 9. out_proj GEMM (bf16 MFMA): 4096 x 1024 x K=2048
  gemm_bf16<<<dim3(D_MODEL / 128, NROWS / 128), dim3(256), 0, stream>>>(
      ybuf, owbf, outpre, D_MODEL, D_INNER);

  // 10. layernorm + residual
  ln_kernel<<<dim3(NROWS), dim3(256), 0, stream>>>(
      outpre, x, ln_g, ln_b, out);
}

// Round 5
// 322.277 us; speedup vs baseline: 9.5584x; 1.0920x over previous
//
#include <hip/hip_runtime.h>
#include <math.h>

#define D_MODEL   1024
#define D_INNER   2048
#define HEADDIM   64
#define NHEADS    32
#define D_STATE   128
#define D_CONV    4
#define CONV_DIM  2304      // D_INNER + 2*D_STATE
#define D_IN_PROJ 4384      // 2*D_INNER + 2*D_STATE + NHEADS
#define NPAD      4480      // D_IN_PROJ padded to multiple of 128
#define LSEQ      2048
#define BATCH     2
#define NROWS     4096      // BATCH * LSEQ
#define NC        32        // chunks per batch (LSEQ / 64)

typedef __attribute__((ext_vector_type(8))) short short8_t;
typedef __attribute__((ext_vector_type(4))) float f32x4;

#define MFMA16(a, b, c) __builtin_amdgcn_mfma_f32_16x16x32_bf16(a, b, c, 0, 0, 0)

// async global->LDS, 16B per lane (dest is wave-uniform base + lane*16)
#define GLDS(g, l) __builtin_amdgcn_global_load_lds( \
    (const __attribute__((address_space(1))) unsigned int*)(g), \
    (__attribute__((address_space(3))) unsigned int*)(l), 16, 0, 0)

__device__ __forceinline__ unsigned short f2bf(float f) {
  union { float f; unsigned int u; } v; v.f = f;
  unsigned int u = v.u + 0x7FFFu + ((v.u >> 16) & 1u);
  return (unsigned short)(u >> 16);
}
__device__ __forceinline__ float bf2f(unsigned short h) {
  union { unsigned int u; float f; } v; v.u = ((unsigned int)h) << 16;
  return v.f;
}

// XOR-swizzled LDS helpers (bf16 storage, swizzle byte ^= (row&7)<<4)
__device__ __forceinline__ short8_t lds_frag(const unsigned short* base, int row,
                                             int col, int rowlen) {
  int off = (row * rowlen + col) * 2;
  off ^= (row & 7) << 4;
  return *reinterpret_cast<const short8_t*>(
      reinterpret_cast<const char*>(base) + off);
}
__device__ __forceinline__ void lds_w32(unsigned short* base, int row, int col,
                                        int rowlen, unsigned int val) {
  int off = (row * rowlen + col) * 2;
  off ^= (row & 7) << 4;
  *reinterpret_cast<unsigned int*>(reinterpret_cast<char*>(base) + off) = val;
}
__device__ __forceinline__ void lds_w16(unsigned short* base, int row, int col,
                                        int rowlen, unsigned short val) {
  int off = (row * rowlen + col) * 2;
  off ^= (row & 7) << 4;
  *reinterpret_cast<unsigned short*>(reinterpret_cast<char*>(base) + off) = val;
}
__device__ __forceinline__ unsigned short lds_r16(const unsigned short* base,
                                                  int row, int col, int rowlen) {
  int off = (row * rowlen + col) * 2;
  off ^= (row & 7) << 4;
  return *reinterpret_cast<const unsigned short*>(
      reinterpret_cast<const char*>(base) + off);
}

// ---------------------------------------------------------------------------
// bf16 MFMA GEMM (NT). MODE 0: fp32 C.  MODE 1: bf16 C + fp32 dtraw for the
// last 32 columns.  XCD-bijective block swizzle (requires nwg % 8 == 0).
// ---------------------------------------------------------------------------
template <int MODE>
__global__ __launch_bounds__(256) void gemm_bf16(
    const unsigned short* __restrict__ A, const unsigned short* __restrict__ B,
    void* __restrict__ Cout, float* __restrict__ dtraw, int N, int K) {
  __shared__ unsigned short sA[128 * 64];
  __shared__ unsigned short sB[128 * 64];
  const int tid = threadIdx.x;
  // XCD swizzle
  const int lin = blockIdx.y * gridDim.x + blockIdx.x;
  const int cpx = (gridDim.x * gridDim.y) >> 3;
  const int swz = (lin & 7) * cpx + (lin >> 3);
  const int row0 = (swz / gridDim.x) * 128;
  const int col0 = (swz % gridDim.x) * 128;

  const int l  = tid & 63;
  const int la = l & 15;
  const int lk = (l >> 4) * 8;
  const int w  = tid >> 6;
  const int wr = (w >> 1) * 64;
  const int wc = (w & 1) * 64;

  f32x4 acc[4][4];
  #pragma unroll
  for (int i = 0; i < 4; ++i)
    #pragma unroll
    for (int j = 0; j < 4; ++j) acc[i][j] = (f32x4){0.f, 0.f, 0.f, 0.f};

  for (int k0 = 0; k0 < K; k0 += 64) {
    __syncthreads();
    #pragma unroll
    for (int i = 0; i < 4; ++i) {
      int s = i * 256 + tid;       // 0..1023 16B slots
      int r = s >> 3;              // tile row 0..127
      int j = s & 7;               // 16B block within row
      int jc = j ^ (r & 7);        // inverse-swizzled source block
      GLDS(&A[(size_t)(row0 + r) * K + k0 + jc * 8], &sA[s * 8]);
      GLDS(&B[(size_t)(col0 + r) * K + k0 + jc * 8], &sB[s * 8]);
    }
    __syncthreads();

    #pragma unroll
    for (int kk = 0; kk < 2; ++kk) {
      short8_t af[4], bfr[4];
      #pragma unroll
      for (int mi = 0; mi < 4; ++mi)
        af[mi] = lds_frag(sA, wr + mi * 16 + la, kk * 32 + lk, 64);
      #pragma unroll
      for (int ni = 0; ni < 4; ++ni)
        bfr[ni] = lds_frag(sB, wc + ni * 16 + la, kk * 32 + lk, 64);
      #pragma unroll
      for (int mi = 0; mi < 4; ++mi)
        #pragma unroll
        for (int ni = 0; ni < 4; ++ni)
          acc[mi][ni] = MFMA16(af[mi], bfr[ni], acc[mi][ni]);
    }
  }

  #pragma unroll
  for (int mi = 0; mi < 4; ++mi)
    #pragma unroll
    for (int ni = 0; ni < 4; ++ni)
      #pragma unroll
      for (int r = 0; r < 4; ++r) {
        int gm = row0 + wr + mi * 16 + (l >> 4) * 4 + r;
        int gn = col0 + wc + ni * 16 + la;
        if (gn < N) {
          if constexpr (MODE == 0) {
            ((float*)Cout)[(size_t)gm * N + gn] = acc[mi][ni][r];
          } else {
            ((unsigned short*)Cout)[(size_t)gm * N + gn] = f2bf(acc[mi][ni][r]);
            if (gn >= N - 32) dtraw[(size_t)gm * 32 + (gn - (N - 32))] = acc[mi][ni][r];
          }
        }
      }
}

// ---------------------------------------------------------------------------
// fp32 -> bf16 converts
// ---------------------------------------------------------------------------
__global__ __launch_bounds__(256) void cvt_bf16_kernel(
    const float* __restrict__ src, unsigned short* __restrict__ dst) {
  long i = (long)blockIdx.x * 256 + threadIdx.x;
  float4 a = *reinterpret_cast<const float4*>(&src[i * 8]);
  float4 b = *reinterpret_cast<const float4*>(&src[i * 8 + 4]);
  short8_t o;
  o[0] = (short)f2bf(a.x); o[1] = (short)f2bf(a.y);
  o[2] = (short)f2bf(a.z); o[3] = (short)f2bf(a.w);
  o[4] = (short)f2bf(b.x); o[5] = (short)f2bf(b.y);
  o[6] = (short)f2bf(b.z); o[7] = (short)f2bf(b.w);
  *reinterpret_cast<short8_t*>(&dst[i * 8]) = o;
}

// in_proj_w (4384 x 1024) -> bf16 padded to 4480 rows (zeros)
__global__ __launch_bounds__(256) void cvt_w_kernel(
    const float* __restrict__ w, unsigned short* __restrict__ wbf) {
  long i = (long)blockIdx.x * 256 + threadIdx.x;   // over NPAD*128
  int row = (int)(i >> 7);
  int c8  = (int)(i & 127) << 3;
  short8_t o = {0, 0, 0, 0, 0, 0, 0, 0};
  if (row < D_IN_PROJ) {
    float4 a = *reinterpret_cast<const float4*>(&w[(size_t)row * D_MODEL + c8]);
    float4 b = *reinterpret_cast<const float4*>(&w[(size_t)row * D_MODEL + c8 + 4]);
    o[0] = (short)f2bf(a.x); o[1] = (short)f2bf(a.y);
    o[2] = (short)f2bf(a.z); o[3] = (short)f2bf(a.w);
    o[4] = (short)f2bf(b.x); o[5] = (short)f2bf(b.y);
    o[6] = (short)f2bf(b.z); o[7] = (short)f2bf(b.w);
  }
  *reinterpret_cast<short8_t*>(&wbf[(size_t)row * D_MODEL + c8]) = o;
}

// ---------------------------------------------------------------------------
// depthwise causal conv (K=4) + bias + silu.  l-strip register rolling:
// thread owns channel c, walks 128 timesteps.  bf16 in/out.
// grid (CONV_DIM/256, LSEQ/128, BATCH)
// ---------------------------------------------------------------------------
__global__ __launch_bounds__(256) void conv_silu_kernel(
    const unsigned short* __restrict__ zxb, const float* __restrict__ conv_w,
    const float* __restrict__ conv_b, unsigned short* __restrict__ xconv) {
  const int c  = blockIdx.x * 256 + threadIdx.x;
  const int l0 = blockIdx.y * 128;
  const int b  = blockIdx.z;
  const unsigned short* src = zxb + ((size_t)b * LSEQ) * D_IN_PROJ + D_INNER + c;
  const float w0 = conv_w[c * 4 + 0], w1 = conv_w[c * 4 + 1];
  const float w2 = conv_w[c * 4 + 2], w3 = conv_w[c * 4 + 3];
  const float bia = conv_b[c];
  float x0 = (l0 >= 3) ? bf2f(src[(size_t)(l0 - 3) * D_IN_PROJ]) : 0.f;
  float x1 = (l0 >= 2) ? bf2f(src[(size_t)(l0 - 2) * D_IN_PROJ]) : 0.f;
  float x2 = (l0 >= 1) ? bf2f(src[(size_t)(l0 - 1) * D_IN_PROJ]) : 0.f;
  unsigned short* dst = xconv + ((size_t)(b * LSEQ + l0)) * CONV_DIM + c;
  #pragma unroll 4
  for (int i = 0; i < 128; ++i) {
    float x3 = bf2f(src[(size_t)(l0 + i) * D_IN_PROJ]);
    float acc = fmaf(w3, x3, fmaf(w2, x2, fmaf(w1, x1, fmaf(w0, x0, bia))));
    float s = acc / (1.f + expf(-acc));
    dst[(size_t)i * CONV_DIM] = f2bf(s);
    x0 = x1; x1 = x2; x2 = x3;
  }
}

// ---------------------------------------------------------------------------
// dt = softplus(dtraw + dt_bias)   (dtraw fp32 side-channel from GEMM)
// ---------------------------------------------------------------------------
__global__ __launch_bounds__(256) void dt_kernel(
    const float* __restrict__ dtraw, const float* __restrict__ dt_bias,
    float* __restrict__ dt_out) {
  int idx = blockIdx.x * 256 + threadIdx.x;
  int h = idx & 31;
  float x = dtraw[idx] + dt_bias[h];
  float dt = (x > 20.f) ? x : log1pf(expf(x));
  dt_out[idx] = dt;
}

// ---------------------------------------------------------------------------
// per-chunk inclusive cumsum of a_t = dt_t * A_h.  one wave per (b,c,h).
// ---------------------------------------------------------------------------
__global__ __launch_bounds__(256) void cumsum_kernel(
    const float* __restrict__ dt_s, const float* __restrict__ A_log,
    float* __restrict__ cumL) {
  int u = blockIdx.x * 4 + (threadIdx.x >> 6);
  int lane = threadIdx.x & 63;
  int h = u & 31;
  int bc = u >> 5;
  int row = bc * 64 + lane;
  float A = -expf(A_log[h]);
  float a = dt_s[(size_t)row * NHEADS + h] * A;
  #pragma unroll
  for (int off = 1; off < 64; off <<= 1) {
    float v = __shfl_up(a, off);
    if (lane >= off) a += v;
  }
  cumL[(size_t)u * 64 + lane] = a;
}

// ---------------------------------------------------------------------------
// chunk state: S^T[p][n] = sum_s w_s x[s][p] B[s][n]   (bf16 xconv input)
// ---------------------------------------------------------------------------
__global__ __launch_bounds__(256) void chunkstate_kernel(
    const unsigned short* __restrict__ xconv, const float* __restrict__ dt_s,
    const float* __restrict__ cumL, unsigned short* __restrict__ S) {
  const int bi = blockIdx.x;
  const int h  = bi & 31;
  const int bc = bi >> 5;
  const int row0 = bc * 64;
  const int tid = threadIdx.x;

  __shared__ unsigned short sBT[128 * 64];   // [n][s]
  __shared__ unsigned short sXT[64 * 64];    // [p][s]  (w-weighted)
  __shared__ float sw[64];

  if (tid < 64) {
    float L   = cumL[(size_t)bi * 64 + tid];
    float L63 = cumL[(size_t)bi * 64 + 63];
    sw[tid] = dt_s[(size_t)(row0 + tid) * NHEADS + h] * expf(L63 - L);
  }
  __syncthreads();

  #pragma unroll
  for (int i = 0; i < 16; ++i) {
    int idx = tid + i * 256;
    int s = idx >> 6, n2 = idx & 63;
    unsigned int v = *reinterpret_cast<const unsigned int*>(
        &xconv[(size_t)(row0 + s) * CONV_DIM + D_INNER + n2 * 2]);
    lds_w16(sBT, n2 * 2 + 0, s, 64, (unsigned short)v);
    lds_w16(sBT, n2 * 2 + 1, s, 64, (unsigned short)(v >> 16));
  }
  #pragma unroll
  for (int i = 0; i < 16; ++i) {
    int idx = tid + i * 256;
    int s = idx >> 6, p = idx & 63;
    float xv = bf2f(xconv[(size_t)(row0 + s) * CONV_DIM + h * HEADDIM + p]);
    lds_w16(sXT, p, s, 64, f2bf(xv * sw[s]));
  }
  __syncthreads();

  const int w  = tid >> 6;
  const int l  = tid & 63;
  const int la = l & 15;
  const int lk = (l >> 4) * 8;

  f32x4 acc[8];
  #pragma unroll
  for (int i = 0; i < 8; ++i) acc[i] = (f32x4){0.f, 0.f, 0.f, 0.f};

  #pragma unroll
  for (int ks = 0; ks < 2; ++ks) {
    short8_t a = lds_frag(sXT, 16 * w + la, ks * 32 + lk, 64);
    #pragma unroll
    for (int ni = 0; ni < 8; ++ni) {
      short8_t b = lds_frag(sBT, ni * 16 + la, ks * 32 + lk, 64);
      acc[ni] = MFMA16(a, b, acc[ni]);
    }
  }

  unsigned short* dst = S + (size_t)bi * (HEADDIM * D_STATE);
  #pragma unroll
  for (int ni = 0; ni < 8; ++ni)
    #pragma unroll
    for (int r = 0; r < 4; ++r) {
      int p = 16 * w + (l >> 4) * 4 + r;
      int n = ni * 16 + la;
      dst[p * D_STATE + n] = f2bf(acc[ni][r]);
    }
}

// ---------------------------------------------------------------------------
// H recurrence, elementwise; in place S -> Hprev.
// ---------------------------------------------------------------------------
__global__ __launch_bounds__(256) void hscan_kernel(
    unsigned short* __restrict__ S, const float* __restrict__ cumL) {
  const int g  = blockIdx.x;
  const int bh = g >> 5;
  const int b  = bh >> 5;
  const int h  = bh & 31;
  const int e  = (g & 31) * 256 + threadIdx.x;

  float H = 0.f;
  #pragma unroll 4
  for (int c = 0; c < NC; ++c) {
    size_t u = (size_t)((b * NC + c) * NHEADS + h);
    float dA = expf(cumL[u * 64 + 63]);
    unsigned short sv = S[u * (HEADDIM * D_STATE) + e];
    S[u * (HEADDIM * D_STATE) + e] = f2bf(H);
    H = dA * H + bf2f(sv);
  }
}

// ---------------------------------------------------------------------------
// fused chunk kernel -> y (bf16);  bf16 xconv input
// ---------------------------------------------------------------------------
__global__ __launch_bounds__(256) void chunk_kernel(
    const unsigned short* __restrict__ xconv, const float* __restrict__ dt_s,
    const float* __restrict__ cumL, const unsigned short* __restrict__ Hprev,
    const float* __restrict__ D_skip, unsigned short* __restrict__ y) {
  const int bi = blockIdx.x;
  const int h  = bi & 31;
  const int bc = bi >> 5;
  const int row0 = bc * 64;
  const int tid = threadIdx.x;

  __shared__ unsigned short sC[64 * 128];
  __shared__ unsigned short sB[64 * 128];
  __shared__ unsigned short sXT[64 * 64];
  __shared__ unsigned short sP[64 * 64];
  __shared__ float sL[64], sdt[64], seL[64];

  if (tid < 64) {
    float L = cumL[(size_t)bi * 64 + tid];
    sL[tid]  = L;
    seL[tid] = expf(L);
    sdt[tid] = dt_s[(size_t)(row0 + tid) * NHEADS + h];
  }

  // stage B (cols 0..127) and C (cols 128..255), short8 loads
  #pragma unroll
  for (int i = 0; i < 8; ++i) {
    int idx = tid + i * 256;       // 0..2047 8-elem slots
    int r = idx >> 5, q = idx & 31;
    short8_t v = *reinterpret_cast<const short8_t*>(
        &xconv[(size_t)(row0 + r) * CONV_DIM + D_INNER + q * 8]);
    unsigned int u0 = (unsigned int)(unsigned short)v[0] |
                      ((unsigned int)(unsigned short)v[1] << 16);
    unsigned int u1 = (unsigned int)(unsigned short)v[2] |
                      ((unsigned int)(unsigned short)v[3] << 16);
    unsigned int u2 = (unsigned int)(unsigned short)v[4] |
                      ((unsigned int)(unsigned short)v[5] << 16);
    unsigned int u3 = (unsigned int)(unsigned short)v[6] |
                      ((unsigned int)(unsigned short)v[7] << 16);
    unsigned short* dstb = (q < 16) ? sB : sC;
    int cq = (q & 15) * 8;
    lds_w32(dstb, r, cq + 0, 128, u0);
    lds_w32(dstb, r, cq + 2, 128, u1);
    lds_w32(dstb, r, cq + 4, 128, u2);
    lds_w32(dstb, r, cq + 6, 128, u3);
  }
  #pragma unroll
  for (int i = 0; i < 16; ++i) {
    int idx = tid + i * 256;
    int s = idx >> 6, p = idx & 63;
    lds_w16(sXT, p, s, 64,
            xconv[(size_t)(row0 + s) * CONV_DIM + h * HEADDIM + p]);
  }
  __syncthreads();

  const int w  = tid >> 6;
  const int l  = tid & 63;
  const int la = l & 15;
  const int lk = (l >> 4) * 8;
  const int t0 = 16 * w;

  f32x4 g[4];
  #pragma unroll
  for (int i = 0; i < 4; ++i) g[i] = (f32x4){0.f, 0.f, 0.f, 0.f};
  #pragma unroll
  for (int ks = 0; ks < 4; ++ks) {
    short8_t a = lds_frag(sC, t0 + la, ks * 32 + lk, 128);
    #pragma unroll
    for (int si = 0; si < 4; ++si) {
      short8_t b = lds_frag(sB, si * 16 + la, ks * 32 + lk, 128);
      g[si] = MFMA16(a, b, g[si]);
    }
  }
  #pragma unroll
  for (int si = 0; si < 4; ++si)
    #pragma unroll
    for (int r = 0; r < 4; ++r) {
      int t = t0 + (l >> 4) * 4 + r;
      int s = si * 16 + la;
      float m = 0.f;
      if (s <= t) m = expf(sL[t] - sL[s]) * sdt[s] * g[si][r];
      lds_w16(sP, t, s, 64, f2bf(m));
    }
  __syncthreads();

  f32x4 o[4];
  #pragma unroll
  for (int i = 0; i < 4; ++i) o[i] = (f32x4){0.f, 0.f, 0.f, 0.f};

  const unsigned short* hb = Hprev + (size_t)bi * (HEADDIM * D_STATE);
  #pragma unroll
  for (int ks = 0; ks < 4; ++ks) {
    short8_t a = lds_frag(sC, t0 + la, ks * 32 + lk, 128);
    #pragma unroll
    for (int si = 0; si < 4; ++si) {
      int p = si * 16 + la;
      short8_t b = *reinterpret_cast<const short8_t*>(
          &hb[p * D_STATE + ks * 32 + lk]);
      o[si] = MFMA16(a, b, o[si]);
    }
  }
  #pragma unroll
  for (int si = 0; si < 4; ++si)
    #pragma unroll
    for (int r = 0; r < 4; ++r) {
      int t = t0 + (l >> 4) * 4 + r;
      o[si][r] *= seL[t];
    }
  #pragma unroll
  for (int ks = 0; ks < 2; ++ks) {
    short8_t a = lds_frag(sP, t0 + la, ks * 32 + lk, 64);
    #pragma unroll
    for (int si = 0; si < 4; ++si) {
      short8_t b = lds_frag(sXT, si * 16 + la, ks * 32 + lk, 64);
      o[si] = MFMA16(a, b, o[si]);
    }
  }
  const float Dh = D_skip[h];
  #pragma unroll
  for (int si = 0; si < 4; ++si)
    #pragma unroll
    for (int r = 0; r < 4; ++r) {
      int t = t0 + (l >> 4) * 4 + r;
      int p = si * 16 + la;
      float xv = bf2f(lds_r16(sXT, p, t, 64));
      y[(size_t)(row0 + t) * D_INNER + h * HEADDIM + p] = f2bf(o[si][r] + Dh * xv);
    }
}

// ---------------------------------------------------------------------------
// y(bf16) = y * silu(z bf16); RMSNorm; in-place, short8 vectorized
// ---------------------------------------------------------------------------
__global__ __launch_bounds__(256) void gate_rms_kernel(
    unsigned short* __restrict__ y, const unsigned short* __restrict__ zxb,
    const float* __restrict__ norm_w) {
  const int row = blockIdx.x;
  const int tid = threadIdx.x;
  short8_t zv = *reinterpret_cast<const short8_t*>(
      &zxb[(size_t)row * D_IN_PROJ + tid * 8]);
  short8_t yv = *reinterpret_cast<short8_t*>(
      &y[(size_t)row * D_INNER + tid * 8]);
  float v[8];
  float acc = 0.f;
  #pragma unroll
  for (int i = 0; i < 8; ++i) {
    float z  = bf2f((unsigned short)zv[i]);
    float ys = bf2f((unsigned short)yv[i]);
    float gz = z / (1.f + expf(-z));
    float val = ys * gz;
    v[i] = val;
    acc = fmaf(val, val, acc);
  }
  #pragma unroll
  for (int off = 32; off; off >>= 1) acc += __shfl_xor(acc, off);
  __shared__ float wsum[4];
  if ((tid & 63) == 0) wsum[tid >> 6] = acc;
  __syncthreads();
  float total = wsum[0] + wsum[1] + wsum[2] + wsum[3];
  float scale = rsqrtf(total / (float)D_INNER + 1e-5f);
  short8_t o;
  #pragma unroll
  for (int i = 0; i < 8; ++i)
    o[i] = (short)f2bf(v[i] * scale * norm_w[tid * 8 + i]);
  *reinterpret_cast<short8_t*>(&y[(size_t)row * D_INNER + tid * 8]) = o;
}

// ---------------------------------------------------------------------------
// LayerNorm + residual
// ---------------------------------------------------------------------------
__global__ __launch_bounds__(256) void ln_kernel(
    const float* __restrict__ o, const float* __restrict__ x,
    const float* __restrict__ lng, const float* __restrict__ lnb,
    float* __restrict__ out) {
  const int row = blockIdx.x;
  const int tid = threadIdx.x;
  float v[4];
  float s = 0.f, s2 = 0.f;
  #pragma unroll
  for (int i = 0; i < 4; ++i) {
    int d = i * 256 + tid;
    float t = o[(size_t)row * D_MODEL + d];
    v[i] = t;
    s += t;
    s2 = fmaf(t, t, s2);
  }
  #pragma unroll
  for (int off = 32; off; off >>= 1) {
    s  += __shfl_xor(s, off);
    s2 += __shfl_xor(s2, off);
  }
  __shared__ float sa[4], sb[4];
  if ((tid & 63) == 0) { sa[tid >> 6] = s; sb[tid >> 6] = s2; }
  __syncthreads();
  s  = sa[0] + sa[1] + sa[2] + sa[3];
  s2 = sb[0] + sb[1] + sb[2] + sb[3];
  float mu  = s / (float)D_MODEL;
  float var = s2 / (float)D_MODEL - mu * mu;
  float inv = rsqrtf(var + 1e-5f);
  #pragma unroll
  for (int i = 0; i < 4; ++i) {
    int d = i * 256 + tid;
    out[(size_t)row * D_MODEL + d] =
        (v[i] - mu) * inv * lng[d] + lnb[d] + x[(size_t)row * D_MODEL + d];
  }
}

// ---------------------------------------------------------------------------
extern "C" void kernel_launch(void* const* d_in, const int* in_sizes, int n_in,
                              void* d_out, int out_size, void* d_ws, size_t ws_size,
                              hipStream_t stream) {
  const float* x         = (const float*)d_in[0];
  const float* in_proj_w = (const float*)d_in[1];
  const float* conv_w    = (const float*)d_in[2];
  const float* conv_b    = (const float*)d_in[3];
  const float* dt_bias   = (const float*)d_in[4];
  const float* A_log     = (const float*)d_in[5];
  const float* D_skip    = (const float*)d_in[6];
  const float* norm_w    = (const float*)d_in[7];
  const float* out_w     = (const float*)d_in[8];
  const float* ln_g      = (const float*)d_in[9];
  const float* ln_b      = (const float*)d_in[10];
  float* out = (float*)d_out;

  char* ws = (char*)d_ws;
  unsigned short* zxb   = (unsigned short*)ws;                       // 4096*4384 bf16
  float* outpre         = (float*)ws;                                // alias (dead z)
  char* p = ws + (size_t)NROWS * D_IN_PROJ * 2;
  float* dtraw = (float*)p;            p += (size_t)NROWS * 32 * 4;
  float* dt_s  = (float*)p;            p += (size_t)NROWS * 32 * 4;
  float* cumL  = (float*)p;            p += (size_t)BATCH * NC * NHEADS * 64 * 4;
  unsigned short* xconv = (unsigned short*)p;  p += (size_t)NROWS * CONV_DIM * 2;
  unsigned short* schp  = (unsigned short*)p;  p += (size_t)BATCH * NC * NHEADS * HEADDIM * D_STATE * 2;
  unsigned short* ybuf  = (unsigned short*)p;  p += (size_t)NROWS * D_INNER * 2;
  unsigned short* xbf   = (unsigned short*)p;  p += (size_t)NROWS * D_MODEL * 2;
  unsigned short* wbf   = (unsigned short*)p;  p += (size_t)NPAD * D_MODEL * 2;
  unsigned short* owbf  = (unsigned short*)p;

  // 0. converts
  cvt_bf16_kernel<<<dim3(NROWS * D_MODEL / 8 / 256), dim3(256), 0, stream>>>(
      x, xbf);
  cvt_w_kernel<<<dim3(NPAD * 128 / 256), dim3(256), 0, stream>>>(
      in_proj_w, wbf);
  cvt_bf16_kernel<<<dim3(D_MODEL * D_INNER / 8 / 256), dim3(256), 0, stream>>>(
      out_w, owbf);

  // 1. in_proj GEMM (bf16 out + fp32 dtraw side-channel)
  gemm_bf16<1><<<dim3(NPAD / 128, NROWS / 128), dim3(256), 0, stream>>>(
      xbf, wbf, zxb, dtraw, D_IN_PROJ, D_MODEL);

  // 2. conv + silu (bf16 in/out, l-strip)
  conv_silu_kernel<<<dim3(CONV_DIM / 256, LSEQ / 128, BATCH), dim3(256), 0, stream>>>(
      zxb, conv_w, conv_b, xconv);

  // 3. dt
  dt_kernel<<<dim3(NROWS * NHEADS / 256), dim3(256), 0, stream>>>(
      dtraw, dt_bias, dt_s);

  // 4. per-chunk cumsum
  cumsum_kernel<<<dim3(BATCH * NC * NHEADS / 4), dim3(256), 0, stream>>>(
      dt_s, A_log, cumL);

  // 5. chunk states S (bf16)
  chunkstate_kernel<<<dim3(BATCH * NC * NHEADS), dim3(256), 0, stream>>>(
      xconv, dt_s, cumL, schp);

  // 6. H recurrence (in place S -> Hprev)
  hscan_kernel<<<dim3(BATCH * NHEADS * 32), dim3(256), 0, stream>>>(
      schp, cumL);

  // 7. fused chunk kernel (writes ybuf bf16)
  chunk_kernel<<<dim3(BATCH * NC * NHEADS), dim3(256), 0, stream>>>(
      xconv, dt_s, cumL, schp, D_skip, ybuf);

  // 8. gate + rmsnorm (in-place bf16)
  gate_rms_kernel<<<dim3(NROWS), dim3(256), 0, stream>>>(
      ybuf, zxb, norm_w);

  // 9. out_proj GEMM (fp32 out into outpre, aliasing dead zxb)
  gemm_bf16<0><<<dim3(D_MODEL / 128, NROWS / 128), dim3(256), 0, stream>>>(
      ybuf, owbf, outpre, nullptr, D_MODEL, D_INNER);

  // 10. layernorm + residual
  ln_kernel<<<dim3(NROWS), dim3(256), 0, stream>>>(
      outpre, x, ln_g, ln_b, out);
}